// Round 1
// baseline (5429.223 us; speedup 1.0000x reference)
//
#include <hip/hip_runtime.h>
#include <cstdint>
#include <cstddef>

#define EPSV 1e-5f

// ---------------------------------------------------------------------------
// Sizes
//   x: [4,2048,64,64]  llf: [4,1024,64,64]  Xf: [4,512,64,64]  N = 4096
// ---------------------------------------------------------------------------

// ---------------- conv 3x3, 2048->512, pad 1 (raw, pre-BN) ----------------
// grid (8 oc-tiles, 32 h-pairs, 4 b), block 256
// thread owns 4oc x 2h x 4w outputs.
__global__ __launch_bounds__(256) void ocr_conv3x3(const float* __restrict__ x,
                                                   const float* __restrict__ Wx,
                                                   float* __restrict__ Xf) {
  __shared__ __align__(16) float xs[8][4][68]; // [cc][row][wp] wp = wi+1, zero-padded
  __shared__ float Ws[72][65];                 // [cc*9+tap][oc] odd stride: conflict-free
  const int t  = threadIdx.x;
  const int tw = t & 15, to = t >> 4;
  const int oc0 = blockIdx.x * 64;
  const int h0  = blockIdx.y * 2;
  const int b   = blockIdx.z;

  float acc[4][2][4];
  #pragma unroll
  for (int i = 0; i < 4; ++i)
    #pragma unroll
    for (int hh = 0; hh < 2; ++hh)
      #pragma unroll
      for (int j = 0; j < 4; ++j) acc[i][hh][j] = 0.f;

  const float* xb = x + (size_t)b * 2048 * 4096;
  const float* wg = Wx + (size_t)oc0 * 18432; // 18432 = 2048*9

  #pragma unroll 1
  for (int c0 = 0; c0 < 2048; c0 += 8) {
    __syncthreads();
    // stage x: 8 channels x 4 rows x 68 (halo + zero pad)
    for (int idx = t; idx < 8 * 4 * 68; idx += 256) {
      int cc  = idx / (4 * 68);
      int rem = idx - cc * (4 * 68);
      int r   = rem / 68;
      int col = rem - r * 68;
      int hh  = h0 - 1 + r;
      int wi  = col - 1;
      float v = 0.f;
      if ((unsigned)hh < 64u && (unsigned)wi < 64u)
        v = xb[(size_t)(c0 + cc) * 4096 + hh * 64 + wi];
      xs[cc][r][col] = v;
    }
    // stage W: 64 oc x 72 (cc,tap) -> transposed [r][oc]
    for (int idx = t; idx < 64 * 72; idx += 256) {
      int oc = idx / 72;
      int r  = idx - oc * 72;
      Ws[r][oc] = wg[(size_t)oc * 18432 + (size_t)c0 * 9 + r];
    }
    __syncthreads();

    #pragma unroll 1
    for (int cc = 0; cc < 8; ++cc) {
      float xv[4][6];
      #pragma unroll
      for (int r = 0; r < 4; ++r) {
        const float* p = &xs[cc][r][4 * tw];
        float4 v4 = *(const float4*)p;
        float2 v2 = *(const float2*)(p + 4);
        xv[r][0] = v4.x; xv[r][1] = v4.y; xv[r][2] = v4.z;
        xv[r][3] = v4.w; xv[r][4] = v2.x; xv[r][5] = v2.y;
      }
      #pragma unroll
      for (int tap = 0; tap < 9; ++tap) {
        const int dh = tap / 3, dw = tap - dh * 3;
        const float* wr = &Ws[cc * 9 + tap][4 * to];
        float w0 = wr[0], w1 = wr[1], w2 = wr[2], w3 = wr[3];
        #pragma unroll
        for (int hh = 0; hh < 2; ++hh) {
          #pragma unroll
          for (int j = 0; j < 4; ++j) {
            float xvv = xv[dh + hh][j + dw];
            acc[0][hh][j] += w0 * xvv;
            acc[1][hh][j] += w1 * xvv;
            acc[2][hh][j] += w2 * xvv;
            acc[3][hh][j] += w3 * xvv;
          }
        }
      }
    }
  }

  #pragma unroll
  for (int i = 0; i < 4; ++i)
    #pragma unroll
    for (int hh = 0; hh < 2; ++hh) {
      float4 v = make_float4(acc[i][hh][0], acc[i][hh][1], acc[i][hh][2], acc[i][hh][3]);
      size_t o = (((size_t)b * 512 + oc0 + 4 * to + i) * 64 + (h0 + hh)) * 64 + 4 * tw;
      *(float4*)&Xf[o] = v;
    }
}

// ---------------- per-channel stats over [4][C][4096] -> scale/shift -------
__global__ __launch_bounds__(256) void ocr_chan_stats(const float* __restrict__ buf,
                                                      const float* __restrict__ gamma,
                                                      const float* __restrict__ beta,
                                                      float* __restrict__ scale,
                                                      float* __restrict__ shift, int C) {
  int c = blockIdx.x, t = threadIdx.x;
  float s = 0.f, q = 0.f;
  for (int b = 0; b < 4; ++b) {
    const float* p = buf + ((size_t)b * C + c) * 4096;
    for (int i = t; i < 4096; i += 256) { float v = p[i]; s += v; q += v * v; }
  }
  __shared__ float ls[256], lq[256];
  ls[t] = s; lq[t] = q; __syncthreads();
  for (int off = 128; off > 0; off >>= 1) {
    if (t < off) { ls[t] += ls[t + off]; lq[t] += lq[t + off]; }
    __syncthreads();
  }
  if (t == 0) {
    float mean = ls[0] / 16384.f;
    float var  = lq[0] / 16384.f - mean * mean;
    float sc   = gamma[c] * rsqrtf(var + EPSV);
    scale[c] = sc; shift[c] = beta[c] - mean * sc;
  }
}

// ---------------- in-place y = relu(x*scale[c]+shift[c]) -------------------
__global__ __launch_bounds__(256) void ocr_bnrelu(float* __restrict__ buf,
                                                  const float* __restrict__ scale,
                                                  const float* __restrict__ shift,
                                                  int C, int n4) {
  for (size_t i = blockIdx.x * 256 + threadIdx.x; i < (size_t)n4; i += (size_t)gridDim.x * 256) {
    float4 v = ((float4*)buf)[i];
    int c = (int)((i >> 10) % (size_t)C); // 1024 float4 per (b,c) row
    float sc = scale[c], sh = shift[c];
    v.x = fmaxf(0.f, v.x * sc + sh);
    v.y = fmaxf(0.f, v.y * sc + sh);
    v.z = fmaxf(0.f, v.z * sc + sh);
    v.w = fmaxf(0.f, v.w * sc + sh);
    ((float4*)buf)[i] = v;
  }
}

// ---------------- L = W_L @ llf + b_L  -> [4,19,4096] ----------------------
// grid (64 h, 4 b); threads: csub(4) x w(64)
__global__ __launch_bounds__(256) void ocr_lproj(const float* __restrict__ llf,
                                                 const float* __restrict__ WL,
                                                 const float* __restrict__ bL,
                                                 float* __restrict__ L) {
  int h = blockIdx.x, b = blockIdx.y;
  int t = threadIdx.x, w = t & 63, csub = t >> 6;
  float acc[19];
  #pragma unroll
  for (int k = 0; k < 19; ++k) acc[k] = 0.f;
  const float* base = llf + ((size_t)b * 1024 + csub * 256) * 4096 + h * 64 + w;
  for (int c = 0; c < 256; ++c) {
    float lv = base[(size_t)c * 4096];
    #pragma unroll
    for (int k = 0; k < 19; ++k) acc[k] += WL[k * 1024 + csub * 256 + c] * lv;
  }
  __shared__ float red[4][64][19];
  #pragma unroll
  for (int k = 0; k < 19; ++k) red[csub][w][k] = acc[k];
  __syncthreads();
  if (csub == 0) {
    #pragma unroll
    for (int k = 0; k < 19; ++k) {
      float s = red[0][w][k] + red[1][w][k] + red[2][w][k] + red[3][w][k] + bL[k];
      L[((size_t)b * 19 + k) * 4096 + h * 64 + w] = s;
    }
  }
}

// ---------------- in-place softmax over last dim (4096) --------------------
__global__ __launch_bounds__(256) void ocr_softmax4096(float* __restrict__ buf) {
  int row = blockIdx.x, t = threadIdx.x;
  float* p = buf + (size_t)row * 4096;
  __shared__ float ls[256];
  float m = -1e30f;
  for (int i = t; i < 4096; i += 256) m = fmaxf(m, p[i]);
  ls[t] = m; __syncthreads();
  for (int off = 128; off > 0; off >>= 1) { if (t < off) ls[t] = fmaxf(ls[t], ls[t + off]); __syncthreads(); }
  m = ls[0]; __syncthreads();
  float s = 0.f;
  for (int i = t; i < 4096; i += 256) { float e = __expf(p[i] - m); p[i] = e; s += e; }
  ls[t] = s; __syncthreads();
  for (int off = 128; off > 0; off >>= 1) { if (t < off) ls[t] += ls[t + off]; __syncthreads(); }
  float inv = 1.f / ls[0];
  for (int i = t; i < 4096; i += 256) p[i] *= inv;
}

// ---------------- f_k[b,c,k] = sum_n M[b,k,n] * Xf[b,c,n] ------------------
// grid (512 c, 4 b)
__global__ __launch_bounds__(256) void ocr_fk(const float* __restrict__ M,
                                              const float* __restrict__ Xf,
                                              float* __restrict__ fk) {
  int c = blockIdx.x, b = blockIdx.y, t = threadIdx.x;
  float acc[19];
  #pragma unroll
  for (int k = 0; k < 19; ++k) acc[k] = 0.f;
  const float* xp = Xf + ((size_t)b * 512 + c) * 4096;
  const float* mp = M + (size_t)b * 19 * 4096;
  for (int n = t; n < 4096; n += 256) {
    float xv = xp[n];
    #pragma unroll
    for (int k = 0; k < 19; ++k) acc[k] += mp[k * 4096 + n] * xv;
  }
  __shared__ float red[19 * 256];
  #pragma unroll
  for (int k = 0; k < 19; ++k) red[k * 256 + t] = acc[k];
  __syncthreads();
  for (int off = 128; off > 0; off >>= 1) {
    if (t < off) {
      #pragma unroll
      for (int k = 0; k < 19; ++k) red[k * 256 + t] += red[k * 256 + t + off];
    }
    __syncthreads();
  }
  if (t < 19) fk[((size_t)b * 512 + c) * 19 + t] = red[t * 256];
}

// ---------------- q/d[b,o,k] = sum_c W[o,c] fk[b,c,k] ----------------------
__global__ __launch_bounds__(256) void ocr_qd(const float* __restrict__ Wm,
                                              const float* __restrict__ fk,
                                              float* __restrict__ out) {
  int tid = blockIdx.x * 256 + threadIdx.x;
  if (tid >= 4 * 256 * 19) return;
  int k = tid % 19, o = (tid / 19) % 256, b = tid / (19 * 256);
  const float* fp = fk + (size_t)b * 512 * 19 + k;
  const float* wp = Wm + (size_t)o * 512;
  float acc = 0.f;
  for (int c = 0; c < 512; ++c) acc += wp[c] * fp[c * 19];
  out[tid] = acc;
}

// ---------------- BN over 76 elems per channel + relu, in place ------------
// buf [4,256,19]; grid 256, block 128
__global__ __launch_bounds__(128) void ocr_bn76(float* __restrict__ buf,
                                                const float* __restrict__ gamma,
                                                const float* __restrict__ beta) {
  int o = blockIdx.x, t = threadIdx.x;
  bool act = t < 76;
  float v = 0.f;
  size_t idx = 0;
  if (act) {
    int b = t / 19, k = t % 19;
    idx = ((size_t)b * 256 + o) * 19 + k;
    v = buf[idx];
  }
  __shared__ float ls[128], lq[128];
  ls[t] = act ? v : 0.f; lq[t] = act ? v * v : 0.f; __syncthreads();
  for (int off = 64; off > 0; off >>= 1) { if (t < off) { ls[t] += ls[t + off]; lq[t] += lq[t + off]; } __syncthreads(); }
  __shared__ float s_sc, s_sh;
  if (t == 0) {
    float mean = ls[0] / 76.f;
    float var  = lq[0] / 76.f - mean * mean;
    float sc   = gamma[o] * rsqrtf(var + EPSV);
    s_sc = sc; s_sh = beta[o] - mean * sc;
  }
  __syncthreads();
  if (act) buf[idx] = fmaxf(0.f, v * s_sc + s_sh);
}

// ---------------- generic tiled GEMM: C[b,O,4096] = A[O,K] @ B[b,K,4096] ---
// B optionally concatenated from two sources along K. grid (64 n, O/64, b)
__global__ __launch_bounds__(256) void ocr_gemm64(const float* __restrict__ A,
                                                  const float* __restrict__ B1,
                                                  const float* __restrict__ B2,
                                                  float* __restrict__ Cm,
                                                  int K, int K1, int O) {
  __shared__ __align__(16) float As[16][68];
  __shared__ __align__(16) float Bs[16][68];
  int t = threadIdx.x, tw = t & 15, to = t >> 4;
  int n0 = blockIdx.x * 64, o0 = blockIdx.y * 64, b = blockIdx.z;
  float acc[4][4];
  #pragma unroll
  for (int i = 0; i < 4; ++i)
    #pragma unroll
    for (int j = 0; j < 4; ++j) acc[i][j] = 0.f;

  for (int k0 = 0; k0 < K; k0 += 16) {
    __syncthreads();
    {
      int idx = t;
      #pragma unroll
      for (int r = 0; r < 4; ++r, idx += 256) {
        int oc = idx >> 4, kk = idx & 15;
        As[kk][oc] = A[(size_t)(o0 + oc) * K + k0 + kk];
      }
    }
    {
      int idx = t;
      #pragma unroll
      for (int r = 0; r < 4; ++r, idx += 256) {
        int kk = idx >> 6, n = idx & 63;
        int kg = k0 + kk;
        const float* src = (kg < K1) ? (B1 + ((size_t)b * K1 + kg) * 4096)
                                     : (B2 + ((size_t)b * (K - K1) + (kg - K1)) * 4096);
        Bs[kk][n] = src[n0 + n];
      }
    }
    __syncthreads();
    #pragma unroll
    for (int kk = 0; kk < 16; ++kk) {
      float4 a4 = *(const float4*)&As[kk][4 * to];
      float4 b4 = *(const float4*)&Bs[kk][4 * tw];
      float av[4] = {a4.x, a4.y, a4.z, a4.w};
      float bv[4] = {b4.x, b4.y, b4.z, b4.w};
      #pragma unroll
      for (int i = 0; i < 4; ++i)
        #pragma unroll
        for (int j = 0; j < 4; ++j) acc[i][j] += av[i] * bv[j];
    }
  }
  #pragma unroll
  for (int i = 0; i < 4; ++i) {
    float4 v = make_float4(acc[i][0], acc[i][1], acc[i][2], acc[i][3]);
    *(float4*)&Cm[((size_t)b * O + o0 + 4 * to + i) * 4096 + n0 + 4 * tw] = v;
  }
}

// ---------------- logit + softmax over nc(19): attn[b,k,n] -----------------
// grid (64 nchunk, 4 b); threads qsub(4) x nl(64)
__global__ __launch_bounds__(256) void ocr_attn(const float* __restrict__ query,
                                                const float* __restrict__ key,
                                                float* __restrict__ attn) {
  int n0 = blockIdx.x * 64, b = blockIdx.y;
  int t = threadIdx.x, nl = t & 63, qsub = t >> 6;
  __shared__ float ql[256 * 19];
  for (int i = t; i < 256 * 19; i += 256) ql[i] = query[(size_t)b * 256 * 19 + i];
  __syncthreads();
  float acc[19];
  #pragma unroll
  for (int k = 0; k < 19; ++k) acc[k] = 0.f;
  const float* kp = key + ((size_t)b * 256 + qsub * 64) * 4096 + n0 + nl;
  for (int q = 0; q < 64; ++q) {
    float kv = kp[(size_t)q * 4096];
    const float* qq = &ql[(qsub * 64 + q) * 19];
    #pragma unroll
    for (int k = 0; k < 19; ++k) acc[k] += qq[k] * kv;
  }
  __shared__ float red[4][64][19];
  #pragma unroll
  for (int k = 0; k < 19; ++k) red[qsub][nl][k] = acc[k];
  __syncthreads();
  if (qsub == 0) {
    float v[19]; float m = -1e30f;
    #pragma unroll
    for (int k = 0; k < 19; ++k) {
      v[k] = red[0][nl][k] + red[1][nl][k] + red[2][nl][k] + red[3][nl][k];
      m = fmaxf(m, v[k]);
    }
    float s = 0.f;
    #pragma unroll
    for (int k = 0; k < 19; ++k) { v[k] = __expf(v[k] - m); s += v[k]; }
    float inv = 1.f / s;
    #pragma unroll
    for (int k = 0; k < 19; ++k)
      attn[((size_t)b * 19 + k) * 4096 + n0 + nl] = v[k] * inv;
  }
}

// ---------------- attn_sum[b,q,n] = sum_k delta[b,q,k] attn[b,k,n] ---------
// grid (4 nchunk, 256 q, 4 b)
__global__ __launch_bounds__(256) void ocr_attnsum(const float* __restrict__ delta2,
                                                   const float* __restrict__ attn,
                                                   float* __restrict__ out) {
  int b = blockIdx.z, q = blockIdx.y;
  int n = blockIdx.x * 1024 + threadIdx.x * 4;
  const float* dp = delta2 + ((size_t)b * 256 + q) * 19;
  float4 acc = make_float4(0.f, 0.f, 0.f, 0.f);
  #pragma unroll
  for (int k = 0; k < 19; ++k) {
    float4 av = *(const float4*)&attn[((size_t)b * 19 + k) * 4096 + n];
    float d = dp[k];
    acc.x += d * av.x; acc.y += d * av.y; acc.z += d * av.z; acc.w += d * av.w;
  }
  *(float4*)&out[((size_t)b * 256 + q) * 4096 + n] = acc;
}

// ---------------- out[b,19,n] = W_out @ X_bar + b_out ----------------------
// grid (64 nchunk, 4 b); threads csub(4) x nl(64)
__global__ __launch_bounds__(256) void ocr_out(const float* __restrict__ Wout,
                                               const float* __restrict__ bout,
                                               const float* __restrict__ Xbar,
                                               float* __restrict__ out) {
  int n0 = blockIdx.x * 64, b = blockIdx.y;
  int t = threadIdx.x, nl = t & 63, csub = t >> 6;
  float acc[19];
  #pragma unroll
  for (int k = 0; k < 19; ++k) acc[k] = 0.f;
  const float* base = Xbar + ((size_t)b * 512 + csub * 128) * 4096 + n0 + nl;
  for (int c = 0; c < 128; ++c) {
    float xv = base[(size_t)c * 4096];
    #pragma unroll
    for (int k = 0; k < 19; ++k) acc[k] += Wout[k * 512 + csub * 128 + c] * xv;
  }
  __shared__ float red[4][64][19];
  #pragma unroll
  for (int k = 0; k < 19; ++k) red[csub][nl][k] = acc[k];
  __syncthreads();
  if (csub == 0) {
    #pragma unroll
    for (int k = 0; k < 19; ++k) {
      float s = red[0][nl][k] + red[1][nl][k] + red[2][nl][k] + red[3][nl][k] + bout[k];
      out[((size_t)b * 19 + k) * 4096 + n0 + nl] = s;
    }
  }
}

// ---------------------------------------------------------------------------
extern "C" void kernel_launch(void* const* d_in, const int* in_sizes, int n_in,
                              void* d_out, int out_size, void* d_ws, size_t ws_size,
                              hipStream_t stream) {
  const float* x    = (const float*)d_in[0];
  const float* llf  = (const float*)d_in[1];
  const float* W_L  = (const float*)d_in[2];
  const float* b_L  = (const float*)d_in[3];
  const float* W_X  = (const float*)d_in[4];
  const float* g_X  = (const float*)d_in[5];
  const float* be_X = (const float*)d_in[6];
  const float* W_phi = (const float*)d_in[7];
  const float* g_phi = (const float*)d_in[8];
  const float* be_phi = (const float*)d_in[9];
  const float* W_psi = (const float*)d_in[10];
  const float* g_psi = (const float*)d_in[11];
  const float* be_psi = (const float*)d_in[12];
  const float* W_delta = (const float*)d_in[13];
  const float* g_delta = (const float*)d_in[14];
  const float* be_delta = (const float*)d_in[15];
  const float* W_rho = (const float*)d_in[16];
  const float* g_rho = (const float*)d_in[17];
  const float* be_rho = (const float*)d_in[18];
  const float* W_g  = (const float*)d_in[19];
  const float* g_g  = (const float*)d_in[20];
  const float* be_g = (const float*)d_in[21];
  const float* W_out = (const float*)d_in[22];
  const float* b_out = (const float*)d_in[23];

  float* ws = (float*)d_ws;
  // workspace layout (floats)
  float* Xf   = ws;                        // 4*512*4096  = 8388608
  float* key  = Xf   + 8388608;            // 4*256*4096  = 4194304
  float* asum = key  + 4194304;            // 4*256*4096  = 4194304
  float* Xobj = asum + 4194304;            // 4*512*4096  = 8388608
  float* Xbar = Xobj + 8388608;            // 4*512*4096  = 8388608
  float* M    = Xbar + 8388608;            // 4*19*4096   = 311296
  float* attn = M    + 311296;             // 311296
  float* fk   = attn + 311296;             // 4*512*19    = 38912
  float* qry  = fk   + 38912;              // 4*256*19    = 19456
  float* dlt  = qry  + 19456;              // 19456
  float* st   = dlt  + 19456;              // stats: 4096 floats
  float* scX = st, *shX = st + 512;
  float* scP = st + 1024, *shP = st + 1280;
  float* scR = st + 1536, *shR = st + 2048;
  float* scG = st + 2560, *shG = st + 3072;

  // 1. conv -> Xf (raw)
  ocr_conv3x3<<<dim3(8, 32, 4), 256, 0, stream>>>(x, W_X, Xf);
  // 2. BN stats + apply (in place)
  ocr_chan_stats<<<dim3(512), 256, 0, stream>>>(Xf, g_X, be_X, scX, shX, 512);
  ocr_bnrelu<<<dim3(2048), 256, 0, stream>>>(Xf, scX, shX, 512, 4 * 512 * 1024);
  // 3. L projection -> M buffer, softmax over N
  ocr_lproj<<<dim3(64, 4), 256, 0, stream>>>(llf, W_L, b_L, M);
  ocr_softmax4096<<<dim3(76), 256, 0, stream>>>(M);
  // 4. f_k
  ocr_fk<<<dim3(512, 4), 256, 0, stream>>>(M, Xf, fk);
  // 5. query / delta + BN76
  ocr_qd<<<dim3(76), 256, 0, stream>>>(W_phi, fk, qry);
  ocr_qd<<<dim3(76), 256, 0, stream>>>(W_delta, fk, dlt);
  ocr_bn76<<<dim3(256), 128, 0, stream>>>(qry, g_phi, be_phi);
  ocr_bn76<<<dim3(256), 128, 0, stream>>>(dlt, g_delta, be_delta);
  // 6. key = W_psi @ Xf, BN+relu in place
  ocr_gemm64<<<dim3(64, 4, 4), 256, 0, stream>>>(W_psi, Xf, nullptr, key, 512, 512, 256);
  ocr_chan_stats<<<dim3(256), 256, 0, stream>>>(key, g_psi, be_psi, scP, shP, 256);
  ocr_bnrelu<<<dim3(2048), 256, 0, stream>>>(key, scP, shP, 256, 4 * 256 * 1024);
  // 7. logits + softmax over nc -> attn
  ocr_attn<<<dim3(64, 4), 256, 0, stream>>>(qry, key, attn);
  // 8. attn_sum
  ocr_attnsum<<<dim3(4, 256, 4), 256, 0, stream>>>(dlt, attn, asum);
  // 9. X_obj = W_rho @ attn_sum, BN+relu
  ocr_gemm64<<<dim3(64, 8, 4), 256, 0, stream>>>(W_rho, asum, nullptr, Xobj, 256, 256, 512);
  ocr_chan_stats<<<dim3(512), 256, 0, stream>>>(Xobj, g_rho, be_rho, scR, shR, 512);
  ocr_bnrelu<<<dim3(2048), 256, 0, stream>>>(Xobj, scR, shR, 512, 4 * 512 * 1024);
  // 10. X_bar = W_g @ concat(Xf, X_obj), BN+relu
  ocr_gemm64<<<dim3(64, 8, 4), 256, 0, stream>>>(W_g, Xf, Xobj, Xbar, 1024, 512, 512);
  ocr_chan_stats<<<dim3(512), 256, 0, stream>>>(Xbar, g_g, be_g, scG, shG, 512);
  ocr_bnrelu<<<dim3(2048), 256, 0, stream>>>(Xbar, scG, shG, 512, 4 * 512 * 1024);
  // 11. output projection
  ocr_out<<<dim3(64, 4), 256, 0, stream>>>(W_out, b_out, Xbar, (float*)d_out);
}

// Round 3
// 1471.488 us; speedup vs baseline: 3.6896x; 3.6896x over previous
//
#include <hip/hip_runtime.h>
#include <hip/hip_bf16.h>
#include <cstdint>
#include <cstddef>

#define EPSV 1e-5f

typedef float f32x4 __attribute__((ext_vector_type(4)));
typedef _Float16 f16x8 __attribute__((ext_vector_type(8)));
typedef unsigned short ushortx8 __attribute__((ext_vector_type(8)));

__device__ __forceinline__ unsigned short f2h(float f) {
  _Float16 h = (_Float16)f;
  return *reinterpret_cast<unsigned short*>(&h);
}

__device__ __forceinline__ void gload16(const void* g, void* l) {
  __builtin_amdgcn_global_load_lds(
      (const __attribute__((address_space(1))) void*)g,
      (__attribute__((address_space(3))) void*)l, 16, 0, 0);
}

// ---------------- x [4,2048,64,64] f32 -> xT [4,66,66,2048] f16 (padded) ---
// grid (4 icb, 64 h, 4 b), block 256
__global__ __launch_bounds__(256) void ocr_cvt_x(const float* __restrict__ x,
                                                 unsigned short* __restrict__ xT) {
  int icb = blockIdx.x, h = blockIdx.y, b = blockIdx.z;
  const float* xp = x + ((size_t)b * 2048 + icb * 512) * 4096 + h * 64;
  unsigned short* op = xT + (((size_t)b * 66 + h + 1) * 66 + 1) * 2048 + icb * 512;
  #pragma unroll 1
  for (int it = 0; it < 16; ++it) {
    int cell = it * 256 + threadIdx.x;
    int icg = cell & 63, w = cell >> 6;
    ushortx8 o;
    #pragma unroll
    for (int j = 0; j < 8; ++j)
      o[j] = f2h(xp[(size_t)(icg * 8 + j) * 4096 + w]);
    *(ushortx8*)&op[(size_t)w * 2048 + icg * 8] = o;
  }
}

// ---------------- W_X [512,2048,3,3] f32 -> WT [9,512,2048] f16 ------------
// grid 4096, block 256: oc = bx>>3, ic = (bx&7)*256 + t
__global__ __launch_bounds__(256) void ocr_cvt_w(const float* __restrict__ Wx,
                                                 unsigned short* __restrict__ WT) {
  int oc = blockIdx.x >> 3;
  int ic = (blockIdx.x & 7) * 256 + threadIdx.x;
  const float* wp = Wx + ((size_t)oc * 2048 + ic) * 9;
  float v[9];
  #pragma unroll
  for (int t = 0; t < 9; ++t) v[t] = wp[t];
  #pragma unroll
  for (int t = 0; t < 9; ++t)
    WT[((size_t)t * 512 + oc) * 2048 + ic] = f2h(v[t]);
}

// ---------------- conv 3x3 2048->512 via f16 MFMA implicit GEMM ------------
// grid 256 (bx = px_tile*4 + oc_tile), block 512 (8 waves)
// block tile: 128 oc x (4 h-rows x 64 w); wave = 64 oc x 64 px (1 h-row)
// LDS A: [tap 9][kg 4][oc 128] cells of 16B (8 ic)   = 73728 B
// LDS B: [row 6][kg 4][col 66] cells (pad to 2048)   = 32768 B
__global__ __launch_bounds__(512, 2) void ocr_conv_mfma(const unsigned short* __restrict__ xT,
                                                        const unsigned short* __restrict__ WT,
                                                        float* __restrict__ Xf) {
  __shared__ __align__(16) short As_s[4608 * 8];  // 73728 B
  __shared__ __align__(16) short Bs_s[2048 * 8];  // 32768 B

  const int t = threadIdx.x;
  const int wv = t >> 6, lane = t & 63;
  const int kg = lane >> 4, lc = lane & 15;
  const int wm = wv >> 2, wn = wv & 3;

  const int oc_tile = blockIdx.x & 3;
  const int px = blockIdx.x >> 2;          // 0..63
  const int oc0 = oc_tile * 128;
  const int b = px >> 4;
  const int h0 = (px & 15) * 4;

  // per-lane global src pointers (advance 64B per K-step = 32 ic)
  const char* aSrc[9];
  #pragma unroll
  for (int j = 0; j < 9; ++j) {
    int cell = (wv * 9 + j) * 64 + lane;
    int ocl = cell & 127, akg = (cell >> 7) & 3, tap = cell >> 9;
    aSrc[j] = (const char*)(WT + ((size_t)tap * 512 + oc0 + ocl) * 2048 + akg * 8);
  }
  const char* bSrc[4];
  #pragma unroll
  for (int j = 0; j < 4; ++j) {
    int cell = (wv * 4 + j) * 64 + lane;
    int cc = cell < 1584 ? cell : 0;
    int col = cc % 66, r2 = cc / 66;
    int bkg = r2 & 3, row = r2 >> 2;
    bSrc[j] = (const char*)(xT + (((size_t)b * 66 + h0 + row) * 66 + col) * 2048 + bkg * 8);
  }

  f32x4 acc[4][4] = {};

  // prologue stage (ic0 = 0)
  #pragma unroll
  for (int j = 0; j < 9; ++j) { gload16(aSrc[j], As_s + (wv * 9 + j) * 512); aSrc[j] += 64; }
  #pragma unroll
  for (int j = 0; j < 4; ++j) { gload16(bSrc[j], Bs_s + (wv * 4 + j) * 512); bSrc[j] += 64; }

  #pragma unroll 1
  for (int step = 0; step < 64; ++step) {
    __syncthreads();   // staged data visible (drains vmcnt)
    #pragma unroll
    for (int dh = 0; dh < 3; ++dh) {
      #pragma unroll
      for (int dw = 0; dw < 3; ++dw) {
        const int tap = dh * 3 + dw;
        f16x8 av[4], bv[4];
        #pragma unroll
        for (int mi = 0; mi < 4; ++mi)
          av[mi] = *(const f16x8*)&As_s[(tap * 512 + kg * 128 + wm * 64 + mi * 16 + lc) * 8];
        #pragma unroll
        for (int ni = 0; ni < 4; ++ni)
          bv[ni] = *(const f16x8*)&Bs_s[((((wn + dh) * 4 + kg) * 66) + ni * 16 + lc + dw) * 8];
        #pragma unroll
        for (int mi = 0; mi < 4; ++mi)
          #pragma unroll
          for (int ni = 0; ni < 4; ++ni)
            acc[mi][ni] = __builtin_amdgcn_mfma_f32_16x16x32_f16(av[mi], bv[ni], acc[mi][ni], 0, 0, 0);
      }
    }
    if (step != 63) {
      __syncthreads();   // all waves done reading before overwrite
      #pragma unroll
      for (int j = 0; j < 9; ++j) { gload16(aSrc[j], As_s + (wv * 9 + j) * 512); aSrc[j] += 64; }
      #pragma unroll
      for (int j = 0; j < 4; ++j) { gload16(bSrc[j], Bs_s + (wv * 4 + j) * 512); bSrc[j] += 64; }
    }
  }

  // epilogue: C/D layout: col = lane&15 (pixel/w), row = (lane>>4)*4 + r (oc)
  const int h = h0 + wn;
  #pragma unroll
  for (int mi = 0; mi < 4; ++mi) {
    #pragma unroll
    for (int ni = 0; ni < 4; ++ni) {
      #pragma unroll
      for (int r = 0; r < 4; ++r) {
        int oc = oc0 + wm * 64 + mi * 16 + (lane >> 4) * 4 + r;
        int w = ni * 16 + lc;
        Xf[(((size_t)b * 512 + oc) * 64 + h) * 64 + w] = acc[mi][ni][r];
      }
    }
  }
}

// ---------------- per-channel stats over [4][C][4096] -> scale/shift -------
__global__ __launch_bounds__(256) void ocr_chan_stats(const float* __restrict__ buf,
                                                      const float* __restrict__ gamma,
                                                      const float* __restrict__ beta,
                                                      float* __restrict__ scale,
                                                      float* __restrict__ shift, int C) {
  int c = blockIdx.x, t = threadIdx.x;
  float s = 0.f, q = 0.f;
  for (int b = 0; b < 4; ++b) {
    const float* p = buf + ((size_t)b * C + c) * 4096;
    for (int i = t; i < 4096; i += 256) { float v = p[i]; s += v; q += v * v; }
  }
  __shared__ float ls[256], lq[256];
  ls[t] = s; lq[t] = q; __syncthreads();
  for (int off = 128; off > 0; off >>= 1) {
    if (t < off) { ls[t] += ls[t + off]; lq[t] += lq[t + off]; }
    __syncthreads();
  }
  if (t == 0) {
    float mean = ls[0] / 16384.f;
    float var  = lq[0] / 16384.f - mean * mean;
    float sc   = gamma[c] * rsqrtf(var + EPSV);
    scale[c] = sc; shift[c] = beta[c] - mean * sc;
  }
}

// ---------------- in-place y = relu(x*scale[c]+shift[c]) -------------------
__global__ __launch_bounds__(256) void ocr_bnrelu(float* __restrict__ buf,
                                                  const float* __restrict__ scale,
                                                  const float* __restrict__ shift,
                                                  int C, int n4) {
  for (size_t i = blockIdx.x * 256 + threadIdx.x; i < (size_t)n4; i += (size_t)gridDim.x * 256) {
    float4 v = ((float4*)buf)[i];
    int c = (int)((i >> 10) % (size_t)C);
    float sc = scale[c], sh = shift[c];
    v.x = fmaxf(0.f, v.x * sc + sh);
    v.y = fmaxf(0.f, v.y * sc + sh);
    v.z = fmaxf(0.f, v.z * sc + sh);
    v.w = fmaxf(0.f, v.w * sc + sh);
    ((float4*)buf)[i] = v;
  }
}

// ---------------- L = W_L @ llf + b_L  -> [4,19,4096] ----------------------
__global__ __launch_bounds__(256) void ocr_lproj(const float* __restrict__ llf,
                                                 const float* __restrict__ WL,
                                                 const float* __restrict__ bL,
                                                 float* __restrict__ L) {
  int h = blockIdx.x, b = blockIdx.y;
  int t = threadIdx.x, w = t & 63, csub = t >> 6;
  float acc[19];
  #pragma unroll
  for (int k = 0; k < 19; ++k) acc[k] = 0.f;
  const float* base = llf + ((size_t)b * 1024 + csub * 256) * 4096 + h * 64 + w;
  for (int c = 0; c < 256; ++c) {
    float lv = base[(size_t)c * 4096];
    #pragma unroll
    for (int k = 0; k < 19; ++k) acc[k] += WL[k * 1024 + csub * 256 + c] * lv;
  }
  __shared__ float red[4][64][19];
  #pragma unroll
  for (int k = 0; k < 19; ++k) red[csub][w][k] = acc[k];
  __syncthreads();
  if (csub == 0) {
    #pragma unroll
    for (int k = 0; k < 19; ++k) {
      float s = red[0][w][k] + red[1][w][k] + red[2][w][k] + red[3][w][k] + bL[k];
      L[((size_t)b * 19 + k) * 4096 + h * 64 + w] = s;
    }
  }
}

// ---------------- in-place softmax over last dim (4096) --------------------
__global__ __launch_bounds__(256) void ocr_softmax4096(float* __restrict__ buf) {
  int row = blockIdx.x, t = threadIdx.x;
  float* p = buf + (size_t)row * 4096;
  __shared__ float ls[256];
  float m = -1e30f;
  for (int i = t; i < 4096; i += 256) m = fmaxf(m, p[i]);
  ls[t] = m; __syncthreads();
  for (int off = 128; off > 0; off >>= 1) { if (t < off) ls[t] = fmaxf(ls[t], ls[t + off]); __syncthreads(); }
  m = ls[0]; __syncthreads();
  float s = 0.f;
  for (int i = t; i < 4096; i += 256) { float e = __expf(p[i] - m); p[i] = e; s += e; }
  ls[t] = s; __syncthreads();
  for (int off = 128; off > 0; off >>= 1) { if (t < off) ls[t] += ls[t + off]; __syncthreads(); }
  float inv = 1.f / ls[0];
  for (int i = t; i < 4096; i += 256) p[i] *= inv;
}

// ---------------- f_k[b,c,k] = sum_n M[b,k,n] * Xf[b,c,n] ------------------
__global__ __launch_bounds__(256) void ocr_fk(const float* __restrict__ M,
                                              const float* __restrict__ Xf,
                                              float* __restrict__ fk) {
  int c = blockIdx.x, b = blockIdx.y, t = threadIdx.x;
  float acc[19];
  #pragma unroll
  for (int k = 0; k < 19; ++k) acc[k] = 0.f;
  const float* xp = Xf + ((size_t)b * 512 + c) * 4096;
  const float* mp = M + (size_t)b * 19 * 4096;
  for (int n = t; n < 4096; n += 256) {
    float xv = xp[n];
    #pragma unroll
    for (int k = 0; k < 19; ++k) acc[k] += mp[k * 4096 + n] * xv;
  }
  __shared__ float red[19 * 256];
  #pragma unroll
  for (int k = 0; k < 19; ++k) red[k * 256 + t] = acc[k];
  __syncthreads();
  for (int off = 128; off > 0; off >>= 1) {
    if (t < off) {
      #pragma unroll
      for (int k = 0; k < 19; ++k) red[k * 256 + t] += red[k * 256 + t + off];
    }
    __syncthreads();
  }
  if (t < 19) fk[((size_t)b * 512 + c) * 19 + t] = red[t * 256];
}

// ---------------- q/d[b,o,k] = sum_c W[o,c] fk[b,c,k] ----------------------
__global__ __launch_bounds__(256) void ocr_qd(const float* __restrict__ Wm,
                                              const float* __restrict__ fk,
                                              float* __restrict__ out) {
  int tid = blockIdx.x * 256 + threadIdx.x;
  if (tid >= 4 * 256 * 19) return;
  int k = tid % 19, o = (tid / 19) % 256, b = tid / (19 * 256);
  const float* fp = fk + (size_t)b * 512 * 19 + k;
  const float* wp = Wm + (size_t)o * 512;
  float acc = 0.f;
  for (int c = 0; c < 512; ++c) acc += wp[c] * fp[c * 19];
  out[tid] = acc;
}

// ---------------- BN over 76 elems per channel + relu, in place ------------
__global__ __launch_bounds__(128) void ocr_bn76(float* __restrict__ buf,
                                                const float* __restrict__ gamma,
                                                const float* __restrict__ beta) {
  int o = blockIdx.x, t = threadIdx.x;
  bool act = t < 76;
  float v = 0.f;
  size_t idx = 0;
  if (act) {
    int b = t / 19, k = t % 19;
    idx = ((size_t)b * 256 + o) * 19 + k;
    v = buf[idx];
  }
  __shared__ float ls[128], lq[128];
  ls[t] = act ? v : 0.f; lq[t] = act ? v * v : 0.f; __syncthreads();
  for (int off = 64; off > 0; off >>= 1) { if (t < off) { ls[t] += ls[t + off]; lq[t] += lq[t + off]; } __syncthreads(); }
  __shared__ float s_sc, s_sh;
  if (t == 0) {
    float mean = ls[0] / 76.f;
    float var  = lq[0] / 76.f - mean * mean;
    float sc   = gamma[o] * rsqrtf(var + EPSV);
    s_sc = sc; s_sh = beta[o] - mean * sc;
  }
  __syncthreads();
  if (act) buf[idx] = fmaxf(0.f, v * s_sc + s_sh);
}

// ---------------- generic tiled GEMM: C[b,O,4096] = A[O,K] @ B[b,K,4096] ---
__global__ __launch_bounds__(256) void ocr_gemm64(const float* __restrict__ A,
                                                  const float* __restrict__ B1,
                                                  const float* __restrict__ B2,
                                                  float* __restrict__ Cm,
                                                  int K, int K1, int O) {
  __shared__ __align__(16) float As[16][68];
  __shared__ __align__(16) float Bs[16][68];
  int t = threadIdx.x, tw = t & 15, to = t >> 4;
  int n0 = blockIdx.x * 64, o0 = blockIdx.y * 64, b = blockIdx.z;
  float acc[4][4];
  #pragma unroll
  for (int i = 0; i < 4; ++i)
    #pragma unroll
    for (int j = 0; j < 4; ++j) acc[i][j] = 0.f;

  for (int k0 = 0; k0 < K; k0 += 16) {
    __syncthreads();
    {
      int idx = t;
      #pragma unroll
      for (int r = 0; r < 4; ++r, idx += 256) {
        int oc = idx >> 4, kk = idx & 15;
        As[kk][oc] = A[(size_t)(o0 + oc) * K + k0 + kk];
      }
    }
    {
      int idx = t;
      #pragma unroll
      for (int r = 0; r < 4; ++r, idx += 256) {
        int kk = idx >> 6, n = idx & 63;
        int kg = k0 + kk;
        const float* src = (kg < K1) ? (B1 + ((size_t)b * K1 + kg) * 4096)
                                     : (B2 + ((size_t)b * (K - K1) + (kg - K1)) * 4096);
        Bs[kk][n] = src[n0 + n];
      }
    }
    __syncthreads();
    #pragma unroll
    for (int kk = 0; kk < 16; ++kk) {
      float4 a4 = *(const float4*)&As[kk][4 * to];
      float4 b4 = *(const float4*)&Bs[kk][4 * tw];
      float av[4] = {a4.x, a4.y, a4.z, a4.w};
      float bv[4] = {b4.x, b4.y, b4.z, b4.w};
      #pragma unroll
      for (int i = 0; i < 4; ++i)
        #pragma unroll
        for (int j = 0; j < 4; ++j) acc[i][j] += av[i] * bv[j];
    }
  }
  #pragma unroll
  for (int i = 0; i < 4; ++i) {
    float4 v = make_float4(acc[i][0], acc[i][1], acc[i][2], acc[i][3]);
    *(float4*)&Cm[((size_t)b * O + o0 + 4 * to + i) * 4096 + n0 + 4 * tw] = v;
  }
}

// ---------------- logit + softmax over nc(19): attn[b,k,n] -----------------
__global__ __launch_bounds__(256) void ocr_attn(const float* __restrict__ query,
                                                const float* __restrict__ key,
                                                float* __restrict__ attn) {
  int n0 = blockIdx.x * 64, b = blockIdx.y;
  int t = threadIdx.x, nl = t & 63, qsub = t >> 6;
  __shared__ float ql[256 * 19];
  for (int i = t; i < 256 * 19; i += 256) ql[i] = query[(size_t)b * 256 * 19 + i];
  __syncthreads();
  float acc[19];
  #pragma unroll
  for (int k = 0; k < 19; ++k) acc[k] = 0.f;
  const float* kp = key + ((size_t)b * 256 + qsub * 64) * 4096 + n0 + nl;
  for (int q = 0; q < 64; ++q) {
    float kv = kp[(size_t)q * 4096];
    const float* qq = &ql[(qsub * 64 + q) * 19];
    #pragma unroll
    for (int k = 0; k < 19; ++k) acc[k] += qq[k] * kv;
  }
  __shared__ float red[4][64][19];
  #pragma unroll
  for (int k = 0; k < 19; ++k) red[qsub][nl][k] = acc[k];
  __syncthreads();
  if (qsub == 0) {
    float v[19]; float m = -1e30f;
    #pragma unroll
    for (int k = 0; k < 19; ++k) {
      v[k] = red[0][nl][k] + red[1][nl][k] + red[2][nl][k] + red[3][nl][k];
      m = fmaxf(m, v[k]);
    }
    float s = 0.f;
    #pragma unroll
    for (int k = 0; k < 19; ++k) { v[k] = __expf(v[k] - m); s += v[k]; }
    float inv = 1.f / s;
    #pragma unroll
    for (int k = 0; k < 19; ++k)
      attn[((size_t)b * 19 + k) * 4096 + n0 + nl] = v[k] * inv;
  }
}

// ---------------- attn_sum[b,q,n] = sum_k delta[b,q,k] attn[b,k,n] ---------
__global__ __launch_bounds__(256) void ocr_attnsum(const float* __restrict__ delta2,
                                                   const float* __restrict__ attn,
                                                   float* __restrict__ out) {
  int b = blockIdx.z, q = blockIdx.y;
  int n = blockIdx.x * 1024 + threadIdx.x * 4;
  const float* dp = delta2 + ((size_t)b * 256 + q) * 19;
  float4 acc = make_float4(0.f, 0.f, 0.f, 0.f);
  #pragma unroll
  for (int k = 0; k < 19; ++k) {
    float4 av = *(const float4*)&attn[((size_t)b * 19 + k) * 4096 + n];
    float d = dp[k];
    acc.x += d * av.x; acc.y += d * av.y; acc.z += d * av.z; acc.w += d * av.w;
  }
  *(float4*)&out[((size_t)b * 256 + q) * 4096 + n] = acc;
}

// ---------------- out[b,19,n] = W_out @ X_bar + b_out ----------------------
__global__ __launch_bounds__(256) void ocr_out(const float* __restrict__ Wout,
                                               const float* __restrict__ bout,
                                               const float* __restrict__ Xbar,
                                               float* __restrict__ out) {
  int n0 = blockIdx.x * 64, b = blockIdx.y;
  int t = threadIdx.x, nl = t & 63, csub = t >> 6;
  float acc[19];
  #pragma unroll
  for (int k = 0; k < 19; ++k) acc[k] = 0.f;
  const float* base = Xbar + ((size_t)b * 512 + csub * 128) * 4096 + n0 + nl;
  for (int c = 0; c < 128; ++c) {
    float xv = base[(size_t)c * 4096];
    #pragma unroll
    for (int k = 0; k < 19; ++k) acc[k] += Wout[k * 512 + csub * 128 + c] * xv;
  }
  __shared__ float red[4][64][19];
  #pragma unroll
  for (int k = 0; k < 19; ++k) red[csub][nl][k] = acc[k];
  __syncthreads();
  if (csub == 0) {
    #pragma unroll
    for (int k = 0; k < 19; ++k) {
      float s = red[0][nl][k] + red[1][nl][k] + red[2][nl][k] + red[3][nl][k] + bout[k];
      out[((size_t)b * 19 + k) * 4096 + n0 + nl] = s;
    }
  }
}

// ---------------------------------------------------------------------------
extern "C" void kernel_launch(void* const* d_in, const int* in_sizes, int n_in,
                              void* d_out, int out_size, void* d_ws, size_t ws_size,
                              hipStream_t stream) {
  const float* x    = (const float*)d_in[0];
  const float* llf  = (const float*)d_in[1];
  const float* W_L  = (const float*)d_in[2];
  const float* b_L  = (const float*)d_in[3];
  const float* W_X  = (const float*)d_in[4];
  const float* g_X  = (const float*)d_in[5];
  const float* be_X = (const float*)d_in[6];
  const float* W_phi = (const float*)d_in[7];
  const float* g_phi = (const float*)d_in[8];
  const float* be_phi = (const float*)d_in[9];
  const float* W_psi = (const float*)d_in[10];
  const float* g_psi = (const float*)d_in[11];
  const float* be_psi = (const float*)d_in[12];
  const float* W_delta = (const float*)d_in[13];
  const float* g_delta = (const float*)d_in[14];
  const float* be_delta = (const float*)d_in[15];
  const float* W_rho = (const float*)d_in[16];
  const float* g_rho = (const float*)d_in[17];
  const float* be_rho = (const float*)d_in[18];
  const float* W_g  = (const float*)d_in[19];
  const float* g_g  = (const float*)d_in[20];
  const float* be_g = (const float*)d_in[21];
  const float* W_out = (const float*)d_in[22];
  const float* b_out = (const float*)d_in[23];

  float* ws = (float*)d_ws;
  // persistent across whole pipeline:
  float* Xf   = ws;                        // 4*512*4096  = 8388608 floats
  // union region: [xT|WT] during conv prep/conv, then post-conv buffers
  float* U    = ws + 8388608;
  unsigned short* xT = (unsigned short*)U;              // 4*66*66*2048 f16 = 35,684,352
  unsigned short* WT = (unsigned short*)(U + 17842176); // 9*512*2048 f16   = 9,437,184
  // post-conv view of the union region:
  float* key  = U;                         // 4194304
  float* asum = key  + 4194304;            // 4194304
  float* Xobj = asum + 4194304;            // 8388608
  float* Xbar = Xobj + 8388608;            // 8388608
  float* M    = Xbar + 8388608;            // 311296
  float* attn = M    + 311296;             // 311296
  float* fk   = attn + 311296;             // 38912
  float* qry  = fk   + 38912;              // 19456
  float* dlt  = qry  + 19456;              // 19456
  float* st   = dlt  + 19456;              // 4096
  float* scX = st, *shX = st + 512;
  float* scP = st + 1024, *shP = st + 1280;
  float* scR = st + 1536, *shR = st + 2048;
  float* scG = st + 2560, *shG = st + 3072;

  // 0. prep: zero xT (halo padding), convert x -> NHWC f16, W -> tap-major f16
  hipMemsetAsync(xT, 0, (size_t)35684352 * sizeof(unsigned short), stream);
  ocr_cvt_x<<<dim3(4, 64, 4), 256, 0, stream>>>(x, xT);
  ocr_cvt_w<<<dim3(4096), 256, 0, stream>>>(W_X, WT);

  // 1. conv (f16 MFMA implicit GEMM) -> Xf (raw fp32)
  ocr_conv_mfma<<<dim3(256), 512, 0, stream>>>(xT, WT, Xf);

  // 2. BN stats + apply (in place)
  ocr_chan_stats<<<dim3(512), 256, 0, stream>>>(Xf, g_X, be_X, scX, shX, 512);
  ocr_bnrelu<<<dim3(2048), 256, 0, stream>>>(Xf, scX, shX, 512, 4 * 512 * 1024);
  // 3. L projection -> M buffer, softmax over N
  ocr_lproj<<<dim3(64, 4), 256, 0, stream>>>(llf, W_L, b_L, M);
  ocr_softmax4096<<<dim3(76), 256, 0, stream>>>(M);
  // 4. f_k
  ocr_fk<<<dim3(512, 4), 256, 0, stream>>>(M, Xf, fk);
  // 5. query / delta + BN76
  ocr_qd<<<dim3(76), 256, 0, stream>>>(W_phi, fk, qry);
  ocr_qd<<<dim3(76), 256, 0, stream>>>(W_delta, fk, dlt);
  ocr_bn76<<<dim3(256), 128, 0, stream>>>(qry, g_phi, be_phi);
  ocr_bn76<<<dim3(256), 128, 0, stream>>>(dlt, g_delta, be_delta);
  // 6. key = W_psi @ Xf, BN+relu in place
  ocr_gemm64<<<dim3(64, 4, 4), 256, 0, stream>>>(W_psi, Xf, nullptr, key, 512, 512, 256);
  ocr_chan_stats<<<dim3(256), 256, 0, stream>>>(key, g_psi, be_psi, scP, shP, 256);
  ocr_bnrelu<<<dim3(2048), 256, 0, stream>>>(key, scP, shP, 256, 4 * 256 * 1024);
  // 7. logits + softmax over nc -> attn
  ocr_attn<<<dim3(64, 4), 256, 0, stream>>>(qry, key, attn);
  // 8. attn_sum
  ocr_attnsum<<<dim3(4, 256, 4), 256, 0, stream>>>(dlt, attn, asum);
  // 9. X_obj = W_rho @ attn_sum, BN+relu
  ocr_gemm64<<<dim3(64, 8, 4), 256, 0, stream>>>(W_rho, asum, nullptr, Xobj, 256, 256, 512);
  ocr_chan_stats<<<dim3(512), 256, 0, stream>>>(Xobj, g_rho, be_rho, scR, shR, 512);
  ocr_bnrelu<<<dim3(2048), 256, 0, stream>>>(Xobj, scR, shR, 512, 4 * 512 * 1024);
  // 10. X_bar = W_g @ concat(Xf, X_obj), BN+relu
  ocr_gemm64<<<dim3(64, 8, 4), 256, 0, stream>>>(W_g, Xf, Xobj, Xbar, 1024, 512, 512);
  ocr_chan_stats<<<dim3(512), 256, 0, stream>>>(Xbar, g_g, be_g, scG, shG, 512);
  ocr_bnrelu<<<dim3(2048), 256, 0, stream>>>(Xbar, scG, shG, 512, 4 * 512 * 1024);
  // 11. output projection
  ocr_out<<<dim3(64, 4), 256, 0, stream>>>(W_out, b_out, Xbar, (float*)d_out);
}

// Round 5
// 1129.576 us; speedup vs baseline: 4.8064x; 1.3027x over previous
//
#include <hip/hip_runtime.h>
#include <hip/hip_bf16.h>
#include <cstdint>
#include <cstddef>

#define EPSV 1e-5f

typedef float f32x4 __attribute__((ext_vector_type(4)));
typedef _Float16 f16x8 __attribute__((ext_vector_type(8)));
typedef unsigned short ushortx8 __attribute__((ext_vector_type(8)));

__device__ __forceinline__ unsigned short f2h(float f) {
  _Float16 h = (_Float16)f;
  return *reinterpret_cast<unsigned short*>(&h);
}

// LDS dest must be the WAVE-UNIFORM chunk base; HW adds lane*16.
__device__ __forceinline__ void gload16(const void* g, void* l) {
  __builtin_amdgcn_global_load_lds(
      (const __attribute__((address_space(1))) void*)g,
      (__attribute__((address_space(3))) void*)l, 16, 0, 0);
}

// ---------------- x [4,2048,64,64] f32 -> xT [4,66,66,2048] f16 (padded) ---
__global__ __launch_bounds__(256) void ocr_cvt_x(const float* __restrict__ x,
                                                 unsigned short* __restrict__ xT) {
  int icb = blockIdx.x, h = blockIdx.y, b = blockIdx.z;
  const float* xp = x + ((size_t)b * 2048 + icb * 512) * 4096 + h * 64;
  unsigned short* op = xT + (((size_t)b * 66 + h + 1) * 66 + 1) * 2048 + icb * 512;
  #pragma unroll 1
  for (int it = 0; it < 16; ++it) {
    int cell = it * 256 + threadIdx.x;
    int icg = cell & 63, w = cell >> 6;
    ushortx8 o;
    #pragma unroll
    for (int j = 0; j < 8; ++j)
      o[j] = f2h(xp[(size_t)(icg * 8 + j) * 4096 + w]);
    *(ushortx8*)&op[(size_t)w * 2048 + icg * 8] = o;
  }
}

// ---------------- W_X [512,2048,3,3] f32 -> WT [9,512,2048] f16 ------------
__global__ __launch_bounds__(256) void ocr_cvt_w(const float* __restrict__ Wx,
                                                 unsigned short* __restrict__ WT) {
  int oc = blockIdx.x >> 3;
  int ic = (blockIdx.x & 7) * 256 + threadIdx.x;
  const float* wp = Wx + ((size_t)oc * 2048 + ic) * 9;
  float v[9];
  #pragma unroll
  for (int t = 0; t < 9; ++t) v[t] = wp[t];
  #pragma unroll
  for (int t = 0; t < 9; ++t)
    WT[((size_t)t * 512 + oc) * 2048 + ic] = f2h(v[t]);
}

// ---------------- generic f32 -> f16 elementwise ---------------------------
__global__ __launch_bounds__(256) void ocr_cvt_h(const float* __restrict__ in,
                                                 unsigned short* __restrict__ out, int n) {
  int i = blockIdx.x * 256 + threadIdx.x;
  if (i < n) out[i] = f2h(in[i]);
}

// ---------------- conv 3x3 2048->512, f16 MFMA, split-K-in-LDS -------------
// grid 256: oct = bx>>5 (8 x 64oc), hg = (bx>>2)&7 (8 rows), b = bx&3
// 8 waves: ws = wv&3 owns rows {2ws,2ws+1}; kh = wv>>2 owns an ic half.
// wave tile 64oc x 128px. LDS A [tap9][kh2][kg4][66] 76032B +
// B [row10][kh2][kg4][66] 84480B = 160512B. Staging: full-wave chunks with
// wave-uniform LDS bases; 66-col pad cells loaded with clamped (dup) addrs;
// tail chunks overlap (idempotent writes) instead of per-lane masking.
__global__ __launch_bounds__(512, 2) void ocr_conv_mfma(const unsigned short* __restrict__ xT,
                                                        const unsigned short* __restrict__ WT,
                                                        float* __restrict__ Xf) {
  __shared__ __align__(16) char lds_raw[160512];
  short* As_s = (short*)lds_raw;
  short* Bs_s = (short*)(lds_raw + 76032);
  float* red  = (float*)lds_raw;

  const int t = threadIdx.x;
  const int wv = t >> 6, lane = t & 63;
  const int kg = lane >> 4, lc = lane & 15;
  const int ws = wv & 3, kh = wv >> 2;

  const int oct = blockIdx.x >> 5;
  const int hg  = (blockIdx.x >> 2) & 7;
  const int b   = blockIdx.x & 3;
  const int oc0 = oct * 64, h0 = hg * 8;

  // A: 4752 cells. chunks: j<9 -> j*512+wv*64 ; j==9 -> {4608,4672,4688} wv<3
  unsigned aOff[10]; int aLds[10]; bool aGo[10];
  #pragma unroll
  for (int j = 0; j < 10; ++j) {
    int base; bool go = true;
    if (j < 9) base = j * 512 + wv * 64;
    else { base = (wv == 0) ? 4608 : (wv == 1) ? 4672 : 4688; go = (wv < 3); }
    int cell = base + lane;
    int col = cell % 66, r3 = cell / 66;
    int tap = r3 >> 3, skh = (r3 >> 2) & 1, skg = r3 & 3;
    int colc = col < 64 ? col : 63;            // pad cols: load dup, never read
    aGo[j] = go; aLds[j] = base * 16;
    aOff[j] = (unsigned)((((tap * 512 + oc0 + colc) * 2048) + skh * 1024 + skg * 8) * 2);
  }
  // B: 5280 cells. chunks: j<10 -> j*512+wv*64 ; j==10 -> {5120,5184,5216} wv<3
  unsigned bOff[11]; int bLds[11]; bool bGo[11];
  #pragma unroll
  for (int j = 0; j < 11; ++j) {
    int base; bool go = true;
    if (j < 10) base = j * 512 + wv * 64;
    else { base = (wv == 0) ? 5120 : (wv == 1) ? 5184 : 5216; go = (wv < 3); }
    int cell = base + lane;
    int col = cell % 66, r3 = cell / 66;
    int row = r3 >> 3, skh = (r3 >> 2) & 1, skg = r3 & 3;
    bGo[j] = go; bLds[j] = base * 16;
    bOff[j] = (unsigned)(((((size_t)(b * 66 + h0 + row) * 66 + col) * 2048) + skh * 1024 + skg * 8) * 2);
  }
  const char* wb = (const char*)WT;
  const char* xb = (const char*)xT;

  f32x4 acc[4][8] = {};

  #pragma unroll
  for (int j = 0; j < 10; ++j) if (aGo[j]) gload16(wb + aOff[j], (char*)As_s + aLds[j]);
  #pragma unroll
  for (int j = 0; j < 11; ++j) if (bGo[j]) gload16(xb + bOff[j], (char*)Bs_s + bLds[j]);

  #pragma unroll 1
  for (int step = 0; step < 32; ++step) {
    __syncthreads();
    #pragma unroll
    for (int dh = 0; dh < 3; ++dh) {
      #pragma unroll
      for (int dw = 0; dw < 3; ++dw) {
        const int tap = dh * 3 + dw;
        f16x8 av[4];
        #pragma unroll
        for (int mi = 0; mi < 4; ++mi)
          av[mi] = *(const f16x8*)&As_s[((((tap * 2 + kh) * 4 + kg) * 66) + mi * 16 + lc) * 8];
        #pragma unroll
        for (int hh = 0; hh < 2; ++hh) {
          #pragma unroll
          for (int nw = 0; nw < 4; ++nw) {
            f16x8 bv = *(const f16x8*)&Bs_s[(((((2 * ws + hh + dh) * 2 + kh) * 4 + kg) * 66) + nw * 16 + lc + dw) * 8];
            #pragma unroll
            for (int mi = 0; mi < 4; ++mi)
              acc[mi][hh * 4 + nw] = __builtin_amdgcn_mfma_f32_16x16x32_f16(av[mi], bv, acc[mi][hh * 4 + nw], 0, 0, 0);
          }
        }
      }
    }
    if (step != 31) {
      __syncthreads();
      unsigned adv = (unsigned)(step + 1) * 64u;   // 32 ic per step
      #pragma unroll
      for (int j = 0; j < 10; ++j) if (aGo[j]) gload16(wb + aOff[j] + adv, (char*)As_s + aLds[j]);
      #pragma unroll
      for (int j = 0; j < 11; ++j) if (bGo[j]) gload16(xb + bOff[j] + adv, (char*)Bs_s + bLds[j]);
    }
  }

  // split-K reduction through LDS, then write
  __syncthreads();
  if (kh == 1) {
    #pragma unroll
    for (int mi = 0; mi < 4; ++mi)
      #pragma unroll
      for (int ni = 0; ni < 8; ++ni)
        *(f32x4*)&red[((ws * 32 + mi * 8 + ni) * 64 + lane) * 4] = acc[mi][ni];
  }
  __syncthreads();
  if (kh == 0) {
    #pragma unroll
    for (int mi = 0; mi < 4; ++mi) {
      #pragma unroll
      for (int ni = 0; ni < 8; ++ni) {
        f32x4 other = *(const f32x4*)&red[((ws * 32 + mi * 8 + ni) * 64 + lane) * 4];
        f32x4 s = acc[mi][ni] + other;
        int hh = ni >> 2, nw = ni & 3;
        int h = h0 + 2 * ws + hh;
        #pragma unroll
        for (int r = 0; r < 4; ++r) {
          int oc = oc0 + mi * 16 + (lane >> 4) * 4 + r;
          int w = nw * 16 + lc;
          Xf[(((size_t)b * 512 + oc) * 64 + h) * 64 + w] = s[r];
        }
      }
    }
  }
}

// ---------------- f16 MFMA GEMM: C[b,O,4096] = A[O,K] @ B_h[b,4096,LDB] ----
template<int K, int OT, int NT, int NWM, int NWN, int LDB>
__global__ __launch_bounds__(256) void ocr_gemm_h(const unsigned short* __restrict__ Ah,
                                                  const unsigned short* __restrict__ Bh,
                                                  float* __restrict__ Cm, int O) {
  static_assert(NT == 128, "NT fixed");
  constexpr int MI = OT / NWM / 16;
  constexpr int NI = NT / NWN / 16;
  constexpr int SA = OT + 2, SB = NT + 2;
  constexpr int ACELL = 4 * OT / 256;
  __shared__ __align__(16) short As_s[4 * SA * 8];
  __shared__ __align__(16) short Bs_s[4 * SB * 8];

  const int t = threadIdx.x;
  const int wv = t >> 6, lane = t & 63;
  const int kg = lane >> 4, lc = lane & 15;
  const int wm = wv / NWN, wn = wv % NWN;

  const int n0 = blockIdx.x * NT, o0 = blockIdx.y * OT, b = blockIdx.z;

  const char* aBase[ACELL]; int aLds[ACELL];
  #pragma unroll
  for (int r = 0; r < ACELL; ++r) {
    int flat0 = r * 256 + (t & 448);               // wave base
    int flat  = flat0 + lane;
    int kgs = flat / OT, ol = flat % OT;
    aBase[r] = (const char*)(Ah + ((size_t)(o0 + ol)) * K + kgs * 8);
    aLds[r] = ((flat0 / OT) * SA + (flat0 % OT)) * 16;  // wave-uniform
  }
  const char* bBase[2]; int bLds[2];
  #pragma unroll
  for (int r = 0; r < 2; ++r) {
    int flat0 = r * 256 + (t & 448);
    int flat  = flat0 + lane;
    int kgs = flat >> 7, nl = flat & 127;
    bBase[r] = (const char*)(Bh + ((size_t)b * 4096 + n0 + nl) * LDB + kgs * 8);
    bLds[r] = ((flat0 >> 7) * SB + (flat0 & 127)) * 16;
  }

  f32x4 acc[MI][NI] = {};
  #pragma unroll
  for (int r = 0; r < ACELL; ++r) gload16(aBase[r], (char*)As_s + aLds[r]);
  #pragma unroll
  for (int r = 0; r < 2; ++r) gload16(bBase[r], (char*)Bs_s + bLds[r]);

  #pragma unroll 1
  for (int step = 0; step < K / 32; ++step) {
    __syncthreads();
    f16x8 av[MI], bv[NI];
    #pragma unroll
    for (int mi = 0; mi < MI; ++mi)
      av[mi] = *(const f16x8*)&As_s[(kg * SA + wm * (MI * 16) + mi * 16 + lc) * 8];
    #pragma unroll
    for (int ni = 0; ni < NI; ++ni)
      bv[ni] = *(const f16x8*)&Bs_s[(kg * SB + wn * (NI * 16) + ni * 16 + lc) * 8];
    #pragma unroll
    for (int mi = 0; mi < MI; ++mi)
      #pragma unroll
      for (int ni = 0; ni < NI; ++ni)
        acc[mi][ni] = __builtin_amdgcn_mfma_f32_16x16x32_f16(av[mi], bv[ni], acc[mi][ni], 0, 0, 0);
    if (step != K / 32 - 1) {
      __syncthreads();
      unsigned adv = (unsigned)(step + 1) * 64u;
      #pragma unroll
      for (int r = 0; r < ACELL; ++r) gload16(aBase[r] + adv, (char*)As_s + aLds[r]);
      #pragma unroll
      for (int r = 0; r < 2; ++r) gload16(bBase[r] + adv, (char*)Bs_s + bLds[r]);
    }
  }
  #pragma unroll
  for (int mi = 0; mi < MI; ++mi) {
    #pragma unroll
    for (int ni = 0; ni < NI; ++ni) {
      int n = n0 + wn * (NI * 16) + ni * 16 + lc;
      #pragma unroll
      for (int r = 0; r < 4; ++r) {
        int oc = o0 + wm * (MI * 16) + mi * 16 + (lane >> 4) * 4 + r;
        Cm[((size_t)b * O + oc) * 4096 + n] = acc[mi][ni][r];
      }
    }
  }
}

// ---------------- transpose-convert: f32 [b,C,4096] -> f16 [b,4096,1024]+coff
__global__ __launch_bounds__(256) void ocr_t2h(const float* __restrict__ in,
                                               unsigned short* __restrict__ out,
                                               int C, int coff) {
  __shared__ float tile[64][65];
  int n0 = blockIdx.x * 64, c0 = blockIdx.y * 64, b = blockIdx.z;
  int t = threadIdx.x;
  #pragma unroll
  for (int r = 0; r < 16; ++r) {
    int c_l = r * 4 + (t >> 6), n_l = t & 63;
    tile[c_l][n_l] = in[((size_t)(b * C + c0 + c_l)) * 4096 + n0 + n_l];
  }
  __syncthreads();
  int n_l = t >> 2, cb = (t & 3) * 16;
  ushortx8 o0v, o1v;
  #pragma unroll
  for (int j = 0; j < 8; ++j) o0v[j] = f2h(tile[cb + j][n_l]);
  #pragma unroll
  for (int j = 0; j < 8; ++j) o1v[j] = f2h(tile[cb + 8 + j][n_l]);
  size_t base = ((size_t)b * 4096 + n0 + n_l) * 1024 + coff + c0 + cb;
  *(ushortx8*)&out[base] = o0v;
  *(ushortx8*)&out[base + 8] = o1v;
}

// ---------------- per-channel stats over [4][C][4096] -> scale/shift -------
__global__ __launch_bounds__(256) void ocr_chan_stats(const float* __restrict__ buf,
                                                      const float* __restrict__ gamma,
                                                      const float* __restrict__ beta,
                                                      float* __restrict__ scale,
                                                      float* __restrict__ shift, int C) {
  int c = blockIdx.x, t = threadIdx.x;
  float s = 0.f, q = 0.f;
  for (int b = 0; b < 4; ++b) {
    const float* p = buf + ((size_t)b * C + c) * 4096;
    for (int i = t; i < 4096; i += 256) { float v = p[i]; s += v; q += v * v; }
  }
  __shared__ float ls[256], lq[256];
  ls[t] = s; lq[t] = q; __syncthreads();
  for (int off = 128; off > 0; off >>= 1) {
    if (t < off) { ls[t] += ls[t + off]; lq[t] += lq[t + off]; }
    __syncthreads();
  }
  if (t == 0) {
    float mean = ls[0] / 16384.f;
    float var  = lq[0] / 16384.f - mean * mean;
    float sc   = gamma[c] * rsqrtf(var + EPSV);
    scale[c] = sc; shift[c] = beta[c] - mean * sc;
  }
}

// ---------------- in-place y = relu(x*scale[c]+shift[c]) -------------------
__global__ __launch_bounds__(256) void ocr_bnrelu(float* __restrict__ buf,
                                                  const float* __restrict__ scale,
                                                  const float* __restrict__ shift,
                                                  int C, int n4) {
  for (size_t i = blockIdx.x * 256 + threadIdx.x; i < (size_t)n4; i += (size_t)gridDim.x * 256) {
    float4 v = ((float4*)buf)[i];
    int c = (int)((i >> 10) % (size_t)C);
    float sc = scale[c], sh = shift[c];
    v.x = fmaxf(0.f, v.x * sc + sh);
    v.y = fmaxf(0.f, v.y * sc + sh);
    v.z = fmaxf(0.f, v.z * sc + sh);
    v.w = fmaxf(0.f, v.w * sc + sh);
    ((float4*)buf)[i] = v;
  }
}

// ---------------- L = W_L @ llf + b_L  -> [4,19,4096] ----------------------
__global__ __launch_bounds__(256) void ocr_lproj(const float* __restrict__ llf,
                                                 const float* __restrict__ WL,
                                                 const float* __restrict__ bL,
                                                 float* __restrict__ L) {
  int h = blockIdx.x, b = blockIdx.y;
  int t = threadIdx.x, w = t & 63, csub = t >> 6;
  float acc[19];
  #pragma unroll
  for (int k = 0; k < 19; ++k) acc[k] = 0.f;
  const float* base = llf + ((size_t)b * 1024 + csub * 256) * 4096 + h * 64 + w;
  for (int c = 0; c < 256; ++c) {
    float lv = base[(size_t)c * 4096];
    #pragma unroll
    for (int k = 0; k < 19; ++k) acc[k] += WL[k * 1024 + csub * 256 + c] * lv;
  }
  __shared__ float red[4][64][19];
  #pragma unroll
  for (int k = 0; k < 19; ++k) red[csub][w][k] = acc[k];
  __syncthreads();
  if (csub == 0) {
    #pragma unroll
    for (int k = 0; k < 19; ++k) {
      float s = red[0][w][k] + red[1][w][k] + red[2][w][k] + red[3][w][k] + bL[k];
      L[((size_t)b * 19 + k) * 4096 + h * 64 + w] = s;
    }
  }
}

// ---------------- in-place softmax over last dim (4096) --------------------
__global__ __launch_bounds__(256) void ocr_softmax4096(float* __restrict__ buf) {
  int row = blockIdx.x, t = threadIdx.x;
  float* p = buf + (size_t)row * 4096;
  __shared__ float ls[256];
  float m = -1e30f;
  for (int i = t; i < 4096; i += 256) m = fmaxf(m, p[i]);
  ls[t] = m; __syncthreads();
  for (int off = 128; off > 0; off >>= 1) { if (t < off) ls[t] = fmaxf(ls[t], ls[t + off]); __syncthreads(); }
  m = ls[0]; __syncthreads();
  float s = 0.f;
  for (int i = t; i < 4096; i += 256) { float e = __expf(p[i] - m); p[i] = e; s += e; }
  ls[t] = s; __syncthreads();
  for (int off = 128; off > 0; off >>= 1) { if (t < off) ls[t] += ls[t + off]; __syncthreads(); }
  float inv = 1.f / ls[0];
  for (int i = t; i < 4096; i += 256) p[i] *= inv;
}

// ---------------- f_k[b,c,k] = sum_n M[b,k,n] * Xf[b,c,n] ------------------
__global__ __launch_bounds__(256) void ocr_fk(const float* __restrict__ M,
                                              const float* __restrict__ Xf,
                                              float* __restrict__ fk) {
  int c = blockIdx.x, b = blockIdx.y, t = threadIdx.x;
  float acc[19];
  #pragma unroll
  for (int k = 0; k < 19; ++k) acc[k] = 0.f;
  const float* xp = Xf + ((size_t)b * 512 + c) * 4096;
  const float* mp = M + (size_t)b * 19 * 4096;
  for (int n = t; n < 4096; n += 256) {
    float xv = xp[n];
    #pragma unroll
    for (int k = 0; k < 19; ++k) acc[k] += mp[k * 4096 + n] * xv;
  }
  __shared__ float red[19 * 256];
  #pragma unroll
  for (int k = 0; k < 19; ++k) red[k * 256 + t] = acc[k];
  __syncthreads();
  for (int off = 128; off > 0; off >>= 1) {
    if (t < off) {
      #pragma unroll
      for (int k = 0; k < 19; ++k) red[k * 256 + t] += red[k * 256 + t + off];
    }
    __syncthreads();
  }
  if (t < 19) fk[((size_t)b * 512 + c) * 19 + t] = red[t * 256];
}

// ---------------- q/d[b,o,k] = sum_c W[o,c] fk[b,c,k] ----------------------
__global__ __launch_bounds__(256) void ocr_qd(const float* __restrict__ Wm,
                                              const float* __restrict__ fk,
                                              float* __restrict__ out) {
  int tid = blockIdx.x * 256 + threadIdx.x;
  if (tid >= 4 * 256 * 19) return;
  int k = tid % 19, o = (tid / 19) % 256, b = tid / (19 * 256);
  const float* fp = fk + (size_t)b * 512 * 19 + k;
  const float* wp = Wm + (size_t)o * 512;
  float acc = 0.f;
  for (int c = 0; c < 512; ++c) acc += wp[c] * fp[c * 19];
  out[tid] = acc;
}

// ---------------- BN over 76 elems per channel + relu, in place ------------
__global__ __launch_bounds__(128) void ocr_bn76(float* __restrict__ buf,
                                                const float* __restrict__ gamma,
                                                const float* __restrict__ beta) {
  int o = blockIdx.x, t = threadIdx.x;
  bool act = t < 76;
  float v = 0.f;
  size_t idx = 0;
  if (act) {
    int b = t / 19, k = t % 19;
    idx = ((size_t)b * 256 + o) * 19 + k;
    v = buf[idx];
  }
  __shared__ float ls[128], lq[128];
  ls[t] = act ? v : 0.f; lq[t] = act ? v * v : 0.f; __syncthreads();
  for (int off = 64; off > 0; off >>= 1) { if (t < off) { ls[t] += ls[t + off]; lq[t] += lq[t + off]; } __syncthreads(); }
  __shared__ float s_sc, s_sh;
  if (t == 0) {
    float mean = ls[0] / 76.f;
    float var  = lq[0] / 76.f - mean * mean;
    float sc   = gamma[o] * rsqrtf(var + EPSV);
    s_sc = sc; s_sh = beta[o] - mean * sc;
  }
  __syncthreads();
  if (act) buf[idx] = fmaxf(0.f, v * s_sc + s_sh);
}

// ---------------- logit + softmax over nc(19): attn[b,k,n] -----------------
__global__ __launch_bounds__(256) void ocr_attn(const float* __restrict__ query,
                                                const float* __restrict__ key,
                                                float* __restrict__ attn) {
  int n0 = blockIdx.x * 64, b = blockIdx.y;
  int t = threadIdx.x, nl = t & 63, qsub = t >> 6;
  __shared__ float ql[256 * 19];
  for (int i = t; i < 256 * 19; i += 256) ql[i] = query[(size_t)b * 256 * 19 + i];
  __syncthreads();
  float acc[19];
  #pragma unroll
  for (int k = 0; k < 19; ++k) acc[k] = 0.f;
  const float* kp = key + ((size_t)b * 256 + qsub * 64) * 4096 + n0 + nl;
  for (int q = 0; q < 64; ++q) {
    float kv = kp[(size_t)q * 4096];
    const float* qq = &ql[(qsub * 64 + q) * 19];
    #pragma unroll
    for (int k = 0; k < 19; ++k) acc[k] += qq[k] * kv;
  }
  __shared__ float red[4][64][19];
  #pragma unroll
  for (int k = 0; k < 19; ++k) red[qsub][nl][k] = acc[k];
  __syncthreads();
  if (qsub == 0) {
    float v[19]; float m = -1e30f;
    #pragma unroll
    for (int k = 0; k < 19; ++k) {
      v[k] = red[0][nl][k] + red[1][nl][k] + red[2][nl][k] + red[3][nl][k];
      m = fmaxf(m, v[k]);
    }
    float s = 0.f;
    #pragma unroll
    for (int k = 0; k < 19; ++k) { v[k] = __expf(v[k] - m); s += v[k]; }
    float inv = 1.f / s;
    #pragma unroll
    for (int k = 0; k < 19; ++k)
      attn[((size_t)b * 19 + k) * 4096 + n0 + nl] = v[k] * inv;
  }
}

// ---------------- Wd[b,o,k] = sum_q W_rho[o,q] * dlt[b,q,k] ----------------
__global__ __launch_bounds__(256) void ocr_wd(const float* __restrict__ Wrho,
                                              const float* __restrict__ dlt,
                                              float* __restrict__ Wd) {
  int tid = blockIdx.x * 256 + threadIdx.x;
  if (tid >= 4 * 512 * 19) return;
  int k = tid % 19, o = (tid / 19) % 512, b = tid / (19 * 512);
  const float* dp = dlt + (size_t)b * 256 * 19 + k;
  const float* wp = Wrho + (size_t)o * 256;
  float acc = 0.f;
  for (int q = 0; q < 256; ++q) acc += wp[q] * dp[q * 19];
  Wd[tid] = acc;
}

// ---------------- Xobj stats: per o, mean/var of (Wd@attn) over b,n --------
__global__ __launch_bounds__(256) void ocr_xobj_stats(const float* __restrict__ Wd,
                                                      const float* __restrict__ attn,
                                                      const float* __restrict__ gamma,
                                                      const float* __restrict__ beta,
                                                      float* __restrict__ scale,
                                                      float* __restrict__ shift) {
  int o = blockIdx.x, t = threadIdx.x;
  float s = 0.f, q = 0.f;
  for (int b = 0; b < 4; ++b) {
    float wd[19];
    #pragma unroll
    for (int k = 0; k < 19; ++k) wd[k] = Wd[((size_t)b * 512 + o) * 19 + k];
    for (int n = t; n < 4096; n += 256) {
      float v = 0.f;
      #pragma unroll
      for (int k = 0; k < 19; ++k) v += wd[k] * attn[((size_t)b * 19 + k) * 4096 + n];
      s += v; q += v * v;
    }
  }
  __shared__ float ls[256], lq[256];
  ls[t] = s; lq[t] = q; __syncthreads();
  for (int off = 128; off > 0; off >>= 1) {
    if (t < off) { ls[t] += ls[t + off]; lq[t] += lq[t + off]; }
    __syncthreads();
  }
  if (t == 0) {
    float mean = ls[0] / 16384.f;
    float var  = lq[0] / 16384.f - mean * mean;
    float sc   = gamma[o] * rsqrtf(var + EPSV);
    scale[o] = sc; shift[o] = beta[o] - mean * sc;
  }
}

// ---------------- Xobj apply: relu(scale*(Wd@attn)+shift) -> concat f16 ----
__global__ __launch_bounds__(512) void ocr_xobj_apply(const float* __restrict__ Wd,
                                                      const float* __restrict__ attn,
                                                      const float* __restrict__ scale,
                                                      const float* __restrict__ shift,
                                                      unsigned short* __restrict__ ch) {
  __shared__ float al[19][256];
  int n0 = blockIdx.x * 256, b = blockIdx.y, o = threadIdx.x;
  for (int idx = o; idx < 19 * 256; idx += 512) {
    int k = idx >> 8, nl = idx & 255;
    al[k][nl] = attn[((size_t)b * 19 + k) * 4096 + n0 + nl];
  }
  float wd[19];
  #pragma unroll
  for (int k = 0; k < 19; ++k) wd[k] = Wd[((size_t)b * 512 + o) * 19 + k];
  float sc = scale[o], sh = shift[o];
  __syncthreads();
  #pragma unroll 1
  for (int nl = 0; nl < 256; ++nl) {
    float v = 0.f;
    #pragma unroll
    for (int k = 0; k < 19; ++k) v += wd[k] * al[k][nl];
    v = fmaxf(0.f, v * sc + sh);
    ch[((size_t)b * 4096 + n0 + nl) * 1024 + 512 + o] = f2h(v);
  }
}

// ---------------- out[b,19,n] = W_out @ X_bar + b_out ----------------------
__global__ __launch_bounds__(256) void ocr_out(const float* __restrict__ Wout,
                                               const float* __restrict__ bout,
                                               const float* __restrict__ Xbar,
                                               float* __restrict__ out) {
  int n0 = blockIdx.x * 64, b = blockIdx.y;
  int t = threadIdx.x, nl = t & 63, csub = t >> 6;
  float acc[19];
  #pragma unroll
  for (int k = 0; k < 19; ++k) acc[k] = 0.f;
  const float* base = Xbar + ((size_t)b * 512 + csub * 128) * 4096 + n0 + nl;
  for (int c = 0; c < 128; ++c) {
    float xv = base[(size_t)c * 4096];
    #pragma unroll
    for (int k = 0; k < 19; ++k) acc[k] += Wout[k * 512 + csub * 128 + c] * xv;
  }
  __shared__ float red[4][64][19];
  #pragma unroll
  for (int k = 0; k < 19; ++k) red[csub][nl][k] = acc[k];
  __syncthreads();
  if (csub == 0) {
    #pragma unroll
    for (int k = 0; k < 19; ++k) {
      float s = red[0][nl][k] + red[1][nl][k] + red[2][nl][k] + red[3][nl][k] + bout[k];
      out[((size_t)b * 19 + k) * 4096 + n0 + nl] = s;
    }
  }
}

// ---------------------------------------------------------------------------
extern "C" void kernel_launch(void* const* d_in, const int* in_sizes, int n_in,
                              void* d_out, int out_size, void* d_ws, size_t ws_size,
                              hipStream_t stream) {
  const float* x    = (const float*)d_in[0];
  const float* llf  = (const float*)d_in[1];
  const float* W_L  = (const float*)d_in[2];
  const float* b_L  = (const float*)d_in[3];
  const float* W_X  = (const float*)d_in[4];
  const float* g_X  = (const float*)d_in[5];
  const float* be_X = (const float*)d_in[6];
  const float* W_phi = (const float*)d_in[7];
  const float* g_phi = (const float*)d_in[8];
  const float* be_phi = (const float*)d_in[9];
  const float* W_psi = (const float*)d_in[10];
  const float* g_psi = (const float*)d_in[11];
  const float* be_psi = (const float*)d_in[12];
  const float* W_delta = (const float*)d_in[13];
  const float* g_delta = (const float*)d_in[14];
  const float* be_delta = (const float*)d_in[15];
  const float* W_rho = (const float*)d_in[16];
  const float* g_rho = (const float*)d_in[17];
  const float* be_rho = (const float*)d_in[18];
  const float* W_g  = (const float*)d_in[19];
  const float* g_g  = (const float*)d_in[20];
  const float* be_g = (const float*)d_in[21];
  const float* W_out = (const float*)d_in[22];
  const float* b_out = (const float*)d_in[23];

  float* ws = (float*)d_ws;
  float* Xf = ws;                                        // 8388608 fl, persistent
  float* U  = ws + 8388608;
  // conv-stage aliases (dead after conv):
  unsigned short* xT = (unsigned short*)U;               // 35684352 u16 = 17842176 fl
  unsigned short* WT = (unsigned short*)(U + 17842176);  // 9437184 u16 (ends 22560768 fl)
  // post-conv buffers (overlap xT/WT region):
  unsigned short* concat_h = (unsigned short*)U;         // [b][4096][1024] f16 = 8388608 fl
  float* key  = U + 8388608;                             // 4194304 fl
  float* Xbar = U + 12582912;                            // 8388608 fl (ends 20971520)
  // small region beyond WT end (never overlaps conv data):
  float* SM   = U + 22560768;
  float* M     = SM;                                     // 311296
  float* attnb = SM + 311296;                            // 311296
  float* fk    = SM + 622592;                            // 38912
  float* qry   = SM + 661504;                            // 19456
  float* dlt   = SM + 680960;                            // 19456
  float* Wd    = SM + 700416;                            // 38912
  float* st    = SM + 739328;                            // 4096
  unsigned short* Wpsi_h = (unsigned short*)(SM + 743424);  // 131072 u16
  unsigned short* Wg_h   = (unsigned short*)(SM + 808960);  // 524288 u16
  float* scX = st,        *shX = st + 512;
  float* scP = st + 1024, *shP = st + 1280;
  float* scR = st + 1536, *shR = st + 2048;
  float* scG = st + 2560, *shG = st + 3072;

  // 0. prep: halo-zero + f16 conversions
  hipMemsetAsync(xT, 0, (size_t)35684352 * sizeof(unsigned short), stream);
  ocr_cvt_x<<<dim3(4, 64, 4), 256, 0, stream>>>(x, xT);
  ocr_cvt_w<<<dim3(4096), 256, 0, stream>>>(W_X, WT);
  ocr_cvt_h<<<dim3(512), 256, 0, stream>>>(W_psi, Wpsi_h, 131072);
  ocr_cvt_h<<<dim3(2048), 256, 0, stream>>>(W_g, Wg_h, 524288);

  // 1. conv (f16 MFMA, split-K-in-LDS) -> Xf raw fp32
  ocr_conv_mfma<<<dim3(256), 512, 0, stream>>>(xT, WT, Xf);

  // 2. BN(X) + relu in place
  ocr_chan_stats<<<dim3(512), 256, 0, stream>>>(Xf, g_X, be_X, scX, shX, 512);
  ocr_bnrelu<<<dim3(2048), 256, 0, stream>>>(Xf, scX, shX, 512, 4 * 512 * 1024);
  // 3. Xf -> concat_h cols [0,512) f16 transposed
  ocr_t2h<<<dim3(64, 8, 4), 256, 0, stream>>>(Xf, concat_h, 512, 0);
  // 4. region head: L -> softmax -> f_k -> query/delta + BN76
  ocr_lproj<<<dim3(64, 4), 256, 0, stream>>>(llf, W_L, b_L, M);
  ocr_softmax4096<<<dim3(76), 256, 0, stream>>>(M);
  ocr_fk<<<dim3(512, 4), 256, 0, stream>>>(M, Xf, fk);
  ocr_qd<<<dim3(76), 256, 0, stream>>>(W_phi, fk, qry);
  ocr_qd<<<dim3(76), 256, 0, stream>>>(W_delta, fk, dlt);
  ocr_bn76<<<dim3(256), 128, 0, stream>>>(qry, g_phi, be_phi);
  ocr_bn76<<<dim3(256), 128, 0, stream>>>(dlt, g_delta, be_delta);
  // 5. key = BN(relu(W_psi @ Xf)) via f16 MFMA GEMM
  ocr_gemm_h<512, 64, 128, 2, 2, 1024><<<dim3(32, 4, 4), 256, 0, stream>>>(Wpsi_h, concat_h, key, 256);
  ocr_chan_stats<<<dim3(256), 256, 0, stream>>>(key, g_psi, be_psi, scP, shP, 256);
  ocr_bnrelu<<<dim3(2048), 256, 0, stream>>>(key, scP, shP, 256, 4 * 256 * 1024);
  // 6. attention softmax over nc
  ocr_attn<<<dim3(64, 4), 256, 0, stream>>>(qry, key, attnb);
  // 7. X_obj = BN(relu(W_rho @ delta @ attn)) via associativity (K=19)
  ocr_wd<<<dim3(152), 256, 0, stream>>>(W_rho, dlt, Wd);
  ocr_xobj_stats<<<dim3(512), 256, 0, stream>>>(Wd, attnb, g_rho, be_rho, scR, shR);
  ocr_xobj_apply<<<dim3(16, 4), 512, 0, stream>>>(Wd, attnb, scR, shR, concat_h);
  // 8. X_bar = BN(relu(W_g @ concat)) via f16 MFMA GEMM (K=1024)
  ocr_gemm_h<1024, 128, 128, 2, 2, 1024><<<dim3(32, 4, 4), 256, 0, stream>>>(Wg_h, concat_h, Xbar, 512);
  ocr_chan_stats<<<dim3(512), 256, 0, stream>>>(Xbar, g_g, be_g, scG, shG, 512);
  ocr_bnrelu<<<dim3(2048), 256, 0, stream>>>(Xbar, scG, shG, 512, 4 * 512 * 1024);
  // 9. output projection (fp32)
  ocr_out<<<dim3(64, 4), 256, 0, stream>>>(W_out, b_out, Xbar, (float*)d_out);
}

// Round 6
// 964.115 us; speedup vs baseline: 5.6313x; 1.1716x over previous
//
#include <hip/hip_runtime.h>
#include <hip/hip_bf16.h>
#include <cstdint>
#include <cstddef>

#define EPSV 1e-5f

typedef float f32x4 __attribute__((ext_vector_type(4)));
typedef _Float16 f16x8 __attribute__((ext_vector_type(8)));
typedef unsigned short ushortx8 __attribute__((ext_vector_type(8)));

__device__ __forceinline__ unsigned short f2h(float f) {
  _Float16 h = (_Float16)f;
  return *reinterpret_cast<unsigned short*>(&h);
}

// LDS dest must be the WAVE-UNIFORM chunk base; HW adds lane*16.
__device__ __forceinline__ void gload16(const void* g, void* l) {
  __builtin_amdgcn_global_load_lds(
      (const __attribute__((address_space(1))) void*)g,
      (__attribute__((address_space(3))) void*)l, 16, 0, 0);
}

// ---------------- x [4,2048,64,64] f32 -> xT [4,66,66,2048] f16 (padded) ---
__global__ __launch_bounds__(256) void ocr_cvt_x(const float* __restrict__ x,
                                                 unsigned short* __restrict__ xT) {
  int icb = blockIdx.x, h = blockIdx.y, b = blockIdx.z;
  const float* xp = x + ((size_t)b * 2048 + icb * 512) * 4096 + h * 64;
  unsigned short* op = xT + (((size_t)b * 66 + h + 1) * 66 + 1) * 2048 + icb * 512;
  #pragma unroll 1
  for (int it = 0; it < 16; ++it) {
    int cell = it * 256 + threadIdx.x;
    int icg = cell & 63, w = cell >> 6;
    ushortx8 o;
    #pragma unroll
    for (int j = 0; j < 8; ++j)
      o[j] = f2h(xp[(size_t)(icg * 8 + j) * 4096 + w]);
    *(ushortx8*)&op[(size_t)w * 2048 + icg * 8] = o;
  }
}

// ---------------- W_X [512,2048,3,3] f32 -> WT [9,512,2048] f16 ------------
__global__ __launch_bounds__(256) void ocr_cvt_w(const float* __restrict__ Wx,
                                                 unsigned short* __restrict__ WT) {
  int oc = blockIdx.x >> 3;
  int ic = (blockIdx.x & 7) * 256 + threadIdx.x;
  const float* wp = Wx + ((size_t)oc * 2048 + ic) * 9;
  float v[9];
  #pragma unroll
  for (int t = 0; t < 9; ++t) v[t] = wp[t];
  #pragma unroll
  for (int t = 0; t < 9; ++t)
    WT[((size_t)t * 512 + oc) * 2048 + ic] = f2h(v[t]);
}

// ---------------- generic f32 -> f16 elementwise ---------------------------
__global__ __launch_bounds__(256) void ocr_cvt_h(const float* __restrict__ in,
                                                 unsigned short* __restrict__ out, int n) {
  int i = blockIdx.x * 256 + threadIdx.x;
  if (i < n) out[i] = f2h(in[i]);
}

// ---------------- conv 3x3 2048->512, f16 MFMA, tap-split, double-buffered -
// grid 256: hg = bx&7 (XCD-swizzled: each XCD owns one h-group), b=(bx>>3)&3,
// oct = bx>>5. 8 waves: ws = wv&3 owns rows {2ws,2ws+1}; kh = wv>>2 owns a
// TAP half (kh=0: taps 0-3 + tap4/hh0; kh=1: taps 5-8 + tap4/hh1 - balanced
// 144 MFMA each). BK=32 ic/step, 64 steps. Per LDS buffer: A [tap9][kg4][66]
// 38912B (38 chunks) + B [row10][kg4][66] 43008B (42 chunks) = 80KB; two
// buffers = 160KiB exactly. One barrier/step; loads overlap full compute.
// Split-tap reduction (128KB) reuses LDS after the loop.
__global__ __launch_bounds__(512, 2) void ocr_conv_mfma(const unsigned short* __restrict__ xT,
                                                        const unsigned short* __restrict__ WT,
                                                        float* __restrict__ Xf) {
  __shared__ __align__(16) char lds_raw[163840];
  float* red = (float*)lds_raw;

  const int t = threadIdx.x;
  const int wv = t >> 6, lane = t & 63;
  const int kg = lane >> 4, lc = lane & 15;
  const int ws = wv & 3, kh = wv >> 2;
  const int kh4 = kh * 4;

  const int hg  = blockIdx.x & 7;
  const int b   = (blockIdx.x >> 3) & 3;
  const int oct = blockIdx.x >> 5;
  const int oc0 = oct * 64, h0 = hg * 8;

  // 10 staging chunks per wave (80 total: 0-37 A, 38-79 B), full-wave,
  // wave-uniform LDS base, clamped (dup) loads for pad cells (never read).
  const char* gp[10]; int lo[10];
  #pragma unroll
  for (int i = 0; i < 10; ++i) {
    int c = wv * 10 + i;
    if (c < 38) {
      int cell = c * 64 + lane; if (cell > 2375) cell = 2375;
      int r = cell / 66, col = cell - r * 66;
      if (col > 63) col = 63;
      int tap = r >> 2, kgs = r & 3;
      gp[i] = (const char*)WT + (size_t)(((tap * 512 + oc0 + col) * 2048) + kgs * 8) * 2;
      lo[i] = c * 1024;
    } else {
      int c2 = c - 38;
      int cell = c2 * 64 + lane; if (cell > 2639) cell = 2639;
      int r = cell / 66, col = cell - r * 66;
      int row = r >> 2, kgs = r & 3;
      gp[i] = (const char*)xT + (size_t)((((b * 66 + h0 + row) * 66 + col) * 2048) + kgs * 8) * 2;
      lo[i] = 38912 + c2 * 1024;
    }
  }

  f32x4 acc[4][8] = {};

  // prologue: stage step 0 into buffer 0
  #pragma unroll
  for (int i = 0; i < 10; ++i) gload16(gp[i], lds_raw + lo[i]);
  __syncthreads();

  int cur = 0;
  #pragma unroll 1
  for (int step = 0; step < 64; ++step) {
    if (step < 63) {                      // issue next-step loads FIRST
      unsigned adv = (unsigned)(step + 1) * 64u;   // 32 ic = 64B per step
      int nxt = (cur ^ 1) * 81920;
      #pragma unroll
      for (int i = 0; i < 10; ++i) gload16(gp[i] + adv, lds_raw + nxt + lo[i]);
    }
    const short* As = (const short*)(lds_raw + cur * 81920);
    const short* Bs = (const short*)(lds_raw + cur * 81920 + 38912);
    #pragma unroll
    for (int j = 0; j < 5; ++j) {
      const int tap = kh4 + j;            // kh0: 0..4, kh1: 4..8
      const int dh = tap / 3, dw = tap - dh * 3;
      f16x8 av[4];
      #pragma unroll
      for (int mi = 0; mi < 4; ++mi)
        av[mi] = *(const f16x8*)&As[((tap * 4 + kg) * 66 + mi * 16 + lc) * 8];
      const int r0 = 2 * ws + dh;
      if ((tap != 4) || (kh == 0)) {      // hh = 0
        #pragma unroll
        for (int nw = 0; nw < 4; ++nw) {
          f16x8 bv = *(const f16x8*)&Bs[((r0 * 4 + kg) * 66 + nw * 16 + lc + dw) * 8];
          #pragma unroll
          for (int mi = 0; mi < 4; ++mi)
            acc[mi][nw] = __builtin_amdgcn_mfma_f32_16x16x32_f16(av[mi], bv, acc[mi][nw], 0, 0, 0);
        }
      }
      if ((tap != 4) || (kh == 1)) {      // hh = 1
        #pragma unroll
        for (int nw = 0; nw < 4; ++nw) {
          f16x8 bv = *(const f16x8*)&Bs[(((r0 + 1) * 4 + kg) * 66 + nw * 16 + lc + dw) * 8];
          #pragma unroll
          for (int mi = 0; mi < 4; ++mi)
            acc[mi][4 + nw] = __builtin_amdgcn_mfma_f32_16x16x32_f16(av[mi], bv, acc[mi][4 + nw], 0, 0, 0);
        }
      }
    }
    __syncthreads();   // drains staged loads (vmcnt0) + all reads of cur done
    cur ^= 1;
  }

  // split-tap reduction through LDS, then write
  if (kh == 1) {
    #pragma unroll
    for (int mi = 0; mi < 4; ++mi)
      #pragma unroll
      for (int ni = 0; ni < 8; ++ni)
        *(f32x4*)&red[((ws * 32 + mi * 8 + ni) * 64 + lane) * 4] = acc[mi][ni];
  }
  __syncthreads();
  if (kh == 0) {
    #pragma unroll
    for (int mi = 0; mi < 4; ++mi) {
      #pragma unroll
      for (int ni = 0; ni < 8; ++ni) {
        f32x4 other = *(const f32x4*)&red[((ws * 32 + mi * 8 + ni) * 64 + lane) * 4];
        f32x4 s = acc[mi][ni] + other;
        int hh = ni >> 2, nw = ni & 3;
        int h = h0 + 2 * ws + hh;
        #pragma unroll
        for (int r = 0; r < 4; ++r) {
          int oc = oc0 + mi * 16 + (lane >> 4) * 4 + r;
          int w = nw * 16 + lc;
          Xf[(((size_t)b * 512 + oc) * 64 + h) * 64 + w] = s[r];
        }
      }
    }
  }
}

// ---------------- f16 MFMA GEMM: C[b,O,4096] = A[O,K] @ B_h[b,4096,LDB] ----
template<int K, int OT, int NT, int NWM, int NWN, int LDB>
__global__ __launch_bounds__(256) void ocr_gemm_h(const unsigned short* __restrict__ Ah,
                                                  const unsigned short* __restrict__ Bh,
                                                  float* __restrict__ Cm, int O) {
  static_assert(NT == 128, "NT fixed");
  constexpr int MI = OT / NWM / 16;
  constexpr int NI = NT / NWN / 16;
  constexpr int SA = OT + 2, SB = NT + 2;
  constexpr int ACELL = 4 * OT / 256;
  __shared__ __align__(16) short As_s[4 * SA * 8];
  __shared__ __align__(16) short Bs_s[4 * SB * 8];

  const int t = threadIdx.x;
  const int wv = t >> 6, lane = t & 63;
  const int kg = lane >> 4, lc = lane & 15;
  const int wm = wv / NWN, wn = wv % NWN;

  const int n0 = blockIdx.x * NT, o0 = blockIdx.y * OT, b = blockIdx.z;

  const char* aBase[ACELL]; int aLds[ACELL];
  #pragma unroll
  for (int r = 0; r < ACELL; ++r) {
    int flat0 = r * 256 + (t & 448);               // wave base
    int flat  = flat0 + lane;
    int kgs = flat / OT, ol = flat % OT;
    aBase[r] = (const char*)(Ah + ((size_t)(o0 + ol)) * K + kgs * 8);
    aLds[r] = ((flat0 / OT) * SA + (flat0 % OT)) * 16;  // wave-uniform
  }
  const char* bBase[2]; int bLds[2];
  #pragma unroll
  for (int r = 0; r < 2; ++r) {
    int flat0 = r * 256 + (t & 448);
    int flat  = flat0 + lane;
    int kgs = flat >> 7, nl = flat & 127;
    bBase[r] = (const char*)(Bh + ((size_t)b * 4096 + n0 + nl) * LDB + kgs * 8);
    bLds[r] = ((flat0 >> 7) * SB + (flat0 & 127)) * 16;
  }

  f32x4 acc[MI][NI] = {};
  #pragma unroll
  for (int r = 0; r < ACELL; ++r) gload16(aBase[r], (char*)As_s + aLds[r]);
  #pragma unroll
  for (int r = 0; r < 2; ++r) gload16(bBase[r], (char*)Bs_s + bLds[r]);

  #pragma unroll 1
  for (int step = 0; step < K / 32; ++step) {
    __syncthreads();
    f16x8 av[MI], bv[NI];
    #pragma unroll
    for (int mi = 0; mi < MI; ++mi)
      av[mi] = *(const f16x8*)&As_s[(kg * SA + wm * (MI * 16) + mi * 16 + lc) * 8];
    #pragma unroll
    for (int ni = 0; ni < NI; ++ni)
      bv[ni] = *(const f16x8*)&Bs_s[(kg * SB + wn * (NI * 16) + ni * 16 + lc) * 8];
    #pragma unroll
    for (int mi = 0; mi < MI; ++mi)
      #pragma unroll
      for (int ni = 0; ni < NI; ++ni)
        acc[mi][ni] = __builtin_amdgcn_mfma_f32_16x16x32_f16(av[mi], bv[ni], acc[mi][ni], 0, 0, 0);
    if (step != K / 32 - 1) {
      __syncthreads();
      unsigned adv = (unsigned)(step + 1) * 64u;
      #pragma unroll
      for (int r = 0; r < ACELL; ++r) gload16(aBase[r] + adv, (char*)As_s + aLds[r]);
      #pragma unroll
      for (int r = 0; r < 2; ++r) gload16(bBase[r] + adv, (char*)Bs_s + bLds[r]);
    }
  }
  #pragma unroll
  for (int mi = 0; mi < MI; ++mi) {
    #pragma unroll
    for (int ni = 0; ni < NI; ++ni) {
      int n = n0 + wn * (NI * 16) + ni * 16 + lc;
      #pragma unroll
      for (int r = 0; r < 4; ++r) {
        int oc = o0 + wm * (MI * 16) + mi * 16 + (lane >> 4) * 4 + r;
        Cm[((size_t)b * O + oc) * 4096 + n] = acc[mi][ni][r];
      }
    }
  }
}

// ------- transpose-convert + fused BN/relu: f32 [b,C,4096] -> f16 ----------
__global__ __launch_bounds__(256) void ocr_t2h(const float* __restrict__ in,
                                               const float* __restrict__ scale,
                                               const float* __restrict__ shift,
                                               unsigned short* __restrict__ out,
                                               int C, int coff) {
  __shared__ float tile[64][65];
  int n0 = blockIdx.x * 64, c0 = blockIdx.y * 64, b = blockIdx.z;
  int t = threadIdx.x;
  #pragma unroll
  for (int r = 0; r < 16; ++r) {
    int c_l = r * 4 + (t >> 6), n_l = t & 63;
    tile[c_l][n_l] = in[((size_t)(b * C + c0 + c_l)) * 4096 + n0 + n_l];
  }
  __syncthreads();
  int n_l = t >> 2, cb = (t & 3) * 16;
  ushortx8 o0v, o1v;
  #pragma unroll
  for (int j = 0; j < 8; ++j) {
    int c = c0 + cb + j;
    o0v[j] = f2h(fmaxf(0.f, tile[cb + j][n_l] * scale[c] + shift[c]));
  }
  #pragma unroll
  for (int j = 0; j < 8; ++j) {
    int c = c0 + cb + 8 + j;
    o1v[j] = f2h(fmaxf(0.f, tile[cb + 8 + j][n_l] * scale[c] + shift[c]));
  }
  size_t base = ((size_t)b * 4096 + n0 + n_l) * 1024 + coff + c0 + cb;
  *(ushortx8*)&out[base] = o0v;
  *(ushortx8*)&out[base + 8] = o1v;
}

// ---------------- per-channel stats over [4][C][4096] -> scale/shift -------
__global__ __launch_bounds__(256) void ocr_chan_stats(const float* __restrict__ buf,
                                                      const float* __restrict__ gamma,
                                                      const float* __restrict__ beta,
                                                      float* __restrict__ scale,
                                                      float* __restrict__ shift, int C) {
  int c = blockIdx.x, t = threadIdx.x;
  float s = 0.f, q = 0.f;
  for (int b = 0; b < 4; ++b) {
    const float* p = buf + ((size_t)b * C + c) * 4096;
    for (int i = t; i < 4096; i += 256) { float v = p[i]; s += v; q += v * v; }
  }
  __shared__ float ls[256], lq[256];
  ls[t] = s; lq[t] = q; __syncthreads();
  for (int off = 128; off > 0; off >>= 1) {
    if (t < off) { ls[t] += ls[t + off]; lq[t] += lq[t + off]; }
    __syncthreads();
  }
  if (t == 0) {
    float mean = ls[0] / 16384.f;
    float var  = lq[0] / 16384.f - mean * mean;
    float sc   = gamma[c] * rsqrtf(var + EPSV);
    scale[c] = sc; shift[c] = beta[c] - mean * sc;
  }
}

// ---------------- L = W_L @ llf + b_L  -> [4,19,4096] ----------------------
__global__ __launch_bounds__(256) void ocr_lproj(const float* __restrict__ llf,
                                                 const float* __restrict__ WL,
                                                 const float* __restrict__ bL,
                                                 float* __restrict__ L) {
  int h = blockIdx.x, b = blockIdx.y;
  int t = threadIdx.x, w = t & 63, csub = t >> 6;
  float acc[19];
  #pragma unroll
  for (int k = 0; k < 19; ++k) acc[k] = 0.f;
  const float* base = llf + ((size_t)b * 1024 + csub * 256) * 4096 + h * 64 + w;
  for (int c = 0; c < 256; ++c) {
    float lv = base[(size_t)c * 4096];
    #pragma unroll
    for (int k = 0; k < 19; ++k) acc[k] += WL[k * 1024 + csub * 256 + c] * lv;
  }
  __shared__ float red[4][64][19];
  #pragma unroll
  for (int k = 0; k < 19; ++k) red[csub][w][k] = acc[k];
  __syncthreads();
  if (csub == 0) {
    #pragma unroll
    for (int k = 0; k < 19; ++k) {
      float s = red[0][w][k] + red[1][w][k] + red[2][w][k] + red[3][w][k] + bL[k];
      L[((size_t)b * 19 + k) * 4096 + h * 64 + w] = s;
    }
  }
}

// ---------------- in-place softmax over last dim (4096) --------------------
__global__ __launch_bounds__(256) void ocr_softmax4096(float* __restrict__ buf) {
  int row = blockIdx.x, t = threadIdx.x;
  float* p = buf + (size_t)row * 4096;
  __shared__ float ls[256];
  float m = -1e30f;
  for (int i = t; i < 4096; i += 256) m = fmaxf(m, p[i]);
  ls[t] = m; __syncthreads();
  for (int off = 128; off > 0; off >>= 1) { if (t < off) ls[t] = fmaxf(ls[t], ls[t + off]); __syncthreads(); }
  m = ls[0]; __syncthreads();
  float s = 0.f;
  for (int i = t; i < 4096; i += 256) { float e = __expf(p[i] - m); p[i] = e; s += e; }
  ls[t] = s; __syncthreads();
  for (int off = 128; off > 0; off >>= 1) { if (t < off) ls[t] += ls[t + off]; __syncthreads(); }
  float inv = 1.f / ls[0];
  for (int i = t; i < 4096; i += 256) p[i] *= inv;
}

// -------- f_k[b,c,k] = sum_n M[b,k,n] * relu(Xf*sc+sh)[b,c,n] (fused BN) ---
__global__ __launch_bounds__(256) void ocr_fk(const float* __restrict__ M,
                                              const float* __restrict__ Xf,
                                              const float* __restrict__ scale,
                                              const float* __restrict__ shift,
                                              float* __restrict__ fk) {
  int c = blockIdx.x, b = blockIdx.y, t = threadIdx.x;
  float acc[19];
  #pragma unroll
  for (int k = 0; k < 19; ++k) acc[k] = 0.f;
  const float* xp = Xf + ((size_t)b * 512 + c) * 4096;
  const float* mp = M + (size_t)b * 19 * 4096;
  float sc = scale[c], sh = shift[c];
  for (int n = t; n < 4096; n += 256) {
    float xv = fmaxf(0.f, xp[n] * sc + sh);
    #pragma unroll
    for (int k = 0; k < 19; ++k) acc[k] += mp[k * 4096 + n] * xv;
  }
  __shared__ float red[19 * 256];
  #pragma unroll
  for (int k = 0; k < 19; ++k) red[k * 256 + t] = acc[k];
  __syncthreads();
  for (int off = 128; off > 0; off >>= 1) {
    if (t < off) {
      #pragma unroll
      for (int k = 0; k < 19; ++k) red[k * 256 + t] += red[k * 256 + t + off];
    }
    __syncthreads();
  }
  if (t < 19) fk[((size_t)b * 512 + c) * 19 + t] = red[t * 256];
}

// ---------------- q/d[b,o,k] = sum_c W[o,c] fk[b,c,k] ----------------------
__global__ __launch_bounds__(256) void ocr_qd(const float* __restrict__ Wm,
                                              const float* __restrict__ fk,
                                              float* __restrict__ out) {
  int tid = blockIdx.x * 256 + threadIdx.x;
  if (tid >= 4 * 256 * 19) return;
  int k = tid % 19, o = (tid / 19) % 256, b = tid / (19 * 256);
  const float* fp = fk + (size_t)b * 512 * 19 + k;
  const float* wp = Wm + (size_t)o * 512;
  float acc = 0.f;
  for (int c = 0; c < 512; ++c) acc += wp[c] * fp[c * 19];
  out[tid] = acc;
}

// ---------------- BN over 76 elems per channel + relu, in place ------------
__global__ __launch_bounds__(128) void ocr_bn76(float* __restrict__ buf,
                                                const float* __restrict__ gamma,
                                                const float* __restrict__ beta) {
  int o = blockIdx.x, t = threadIdx.x;
  bool act = t < 76;
  float v = 0.f;
  size_t idx = 0;
  if (act) {
    int b = t / 19, k = t % 19;
    idx = ((size_t)b * 256 + o) * 19 + k;
    v = buf[idx];
  }
  __shared__ float ls[128], lq[128];
  ls[t] = act ? v : 0.f; lq[t] = act ? v * v : 0.f; __syncthreads();
  for (int off = 64; off > 0; off >>= 1) { if (t < off) { ls[t] += ls[t + off]; lq[t] += lq[t + off]; } __syncthreads(); }
  __shared__ float s_sc, s_sh;
  if (t == 0) {
    float mean = ls[0] / 76.f;
    float var  = lq[0] / 76.f - mean * mean;
    float sc   = gamma[o] * rsqrtf(var + EPSV);
    s_sc = sc; s_sh = beta[o] - mean * sc;
  }
  __syncthreads();
  if (act) buf[idx] = fmaxf(0.f, v * s_sc + s_sh);
}

// ------- logit + softmax over nc(19), key BN fused: attn[b,k,n] ------------
__global__ __launch_bounds__(256) void ocr_attn(const float* __restrict__ query,
                                                const float* __restrict__ key,
                                                const float* __restrict__ scale,
                                                const float* __restrict__ shift,
                                                float* __restrict__ attn) {
  int n0 = blockIdx.x * 64, b = blockIdx.y;
  int t = threadIdx.x, nl = t & 63, qsub = t >> 6;
  __shared__ float ql[256 * 19];
  for (int i = t; i < 256 * 19; i += 256) ql[i] = query[(size_t)b * 256 * 19 + i];
  __syncthreads();
  float acc[19];
  #pragma unroll
  for (int k = 0; k < 19; ++k) acc[k] = 0.f;
  const float* kp = key + ((size_t)b * 256 + qsub * 64) * 4096 + n0 + nl;
  for (int q = 0; q < 64; ++q) {
    int ch = qsub * 64 + q;
    float kv = fmaxf(0.f, kp[(size_t)q * 4096] * scale[ch] + shift[ch]);
    const float* qq = &ql[ch * 19];
    #pragma unroll
    for (int k = 0; k < 19; ++k) acc[k] += qq[k] * kv;
  }
  __shared__ float red[4][64][19];
  #pragma unroll
  for (int k = 0; k < 19; ++k) red[qsub][nl][k] = acc[k];
  __syncthreads();
  if (qsub == 0) {
    float v[19]; float m = -1e30f;
    #pragma unroll
    for (int k = 0; k < 19; ++k) {
      v[k] = red[0][nl][k] + red[1][nl][k] + red[2][nl][k] + red[3][nl][k];
      m = fmaxf(m, v[k]);
    }
    float s = 0.f;
    #pragma unroll
    for (int k = 0; k < 19; ++k) { v[k] = __expf(v[k] - m); s += v[k]; }
    float inv = 1.f / s;
    #pragma unroll
    for (int k = 0; k < 19; ++k)
      attn[((size_t)b * 19 + k) * 4096 + n0 + nl] = v[k] * inv;
  }
}

// ---------------- Wd[b,o,k] = sum_q W_rho[o,q] * dlt[b,q,k] ----------------
__global__ __launch_bounds__(256) void ocr_wd(const float* __restrict__ Wrho,
                                              const float* __restrict__ dlt,
                                              float* __restrict__ Wd) {
  int tid = blockIdx.x * 256 + threadIdx.x;
  if (tid >= 4 * 512 * 19) return;
  int k = tid % 19, o = (tid / 19) % 512, b = tid / (19 * 512);
  const float* dp = dlt + (size_t)b * 256 * 19 + k;
  const float* wp = Wrho + (size_t)o * 256;
  float acc = 0.f;
  for (int q = 0; q < 256; ++q) acc += wp[q] * dp[q * 19];
  Wd[tid] = acc;
}

// ---------------- Xobj stats: per o, mean/var of (Wd@attn) over b,n --------
__global__ __launch_bounds__(256) void ocr_xobj_stats(const float* __restrict__ Wd,
                                                      const float* __restrict__ attn,
                                                      const float* __restrict__ gamma,
                                                      const float* __restrict__ beta,
                                                      float* __restrict__ scale,
                                                      float* __restrict__ shift) {
  int o = blockIdx.x, t = threadIdx.x;
  float s = 0.f, q = 0.f;
  for (int b = 0; b < 4; ++b) {
    float wd[19];
    #pragma unroll
    for (int k = 0; k < 19; ++k) wd[k] = Wd[((size_t)b * 512 + o) * 19 + k];
    for (int n = t; n < 4096; n += 256) {
      float v = 0.f;
      #pragma unroll
      for (int k = 0; k < 19; ++k) v += wd[k] * attn[((size_t)b * 19 + k) * 4096 + n];
      s += v; q += v * v;
    }
  }
  __shared__ float ls[256], lq[256];
  ls[t] = s; lq[t] = q; __syncthreads();
  for (int off = 128; off > 0; off >>= 1) {
    if (t < off) { ls[t] += ls[t + off]; lq[t] += lq[t + off]; }
    __syncthreads();
  }
  if (t == 0) {
    float mean = ls[0] / 16384.f;
    float var  = lq[0] / 16384.f - mean * mean;
    float sc   = gamma[o] * rsqrtf(var + EPSV);
    scale[o] = sc; shift[o] = beta[o] - mean * sc;
  }
}

// ---------------- Xobj apply: relu(scale*(Wd@attn)+shift) -> concat f16 ----
__global__ __launch_bounds__(512) void ocr_xobj_apply(const float* __restrict__ Wd,
                                                      const float* __restrict__ attn,
                                                      const float* __restrict__ scale,
                                                      const float* __restrict__ shift,
                                                      unsigned short* __restrict__ ch) {
  __shared__ float al[19][256];
  int n0 = blockIdx.x * 256, b = blockIdx.y, o = threadIdx.x;
  for (int idx = o; idx < 19 * 256; idx += 512) {
    int k = idx >> 8, nl = idx & 255;
    al[k][nl] = attn[((size_t)b * 19 + k) * 4096 + n0 + nl];
  }
  float wd[19];
  #pragma unroll
  for (int k = 0; k < 19; ++k) wd[k] = Wd[((size_t)b * 512 + o) * 19 + k];
  float sc = scale[o], sh = shift[o];
  __syncthreads();
  #pragma unroll 1
  for (int nl = 0; nl < 256; ++nl) {
    float v = 0.f;
    #pragma unroll
    for (int k = 0; k < 19; ++k) v += wd[k] * al[k][nl];
    v = fmaxf(0.f, v * sc + sh);
    ch[((size_t)b * 4096 + n0 + nl) * 1024 + 512 + o] = f2h(v);
  }
}

// -------- out[b,19,n] = W_out @ relu(Xbar*sc+sh) + b_out (BN fused) --------
__global__ __launch_bounds__(256) void ocr_out(const float* __restrict__ Wout,
                                               const float* __restrict__ bout,
                                               const float* __restrict__ Xbar,
                                               const float* __restrict__ scale,
                                               const float* __restrict__ shift,
                                               float* __restrict__ out) {
  int n0 = blockIdx.x * 64, b = blockIdx.y;
  int t = threadIdx.x, nl = t & 63, csub = t >> 6;
  float acc[19];
  #pragma unroll
  for (int k = 0; k < 19; ++k) acc[k] = 0.f;
  const float* base = Xbar + ((size_t)b * 512 + csub * 128) * 4096 + n0 + nl;
  for (int c = 0; c < 128; ++c) {
    int ch = csub * 128 + c;
    float xv = fmaxf(0.f, base[(size_t)c * 4096] * scale[ch] + shift[ch]);
    #pragma unroll
    for (int k = 0; k < 19; ++k) acc[k] += Wout[k * 512 + ch] * xv;
  }
  __shared__ float red[4][64][19];
  #pragma unroll
  for (int k = 0; k < 19; ++k) red[csub][nl][k] = acc[k];
  __syncthreads();
  if (csub == 0) {
    #pragma unroll
    for (int k = 0; k < 19; ++k) {
      float s = red[0][nl][k] + red[1][nl][k] + red[2][nl][k] + red[3][nl][k] + bout[k];
      out[((size_t)b * 19 + k) * 4096 + n0 + nl] = s;
    }
  }
}

// ---------------------------------------------------------------------------
extern "C" void kernel_launch(void* const* d_in, const int* in_sizes, int n_in,
                              void* d_out, int out_size, void* d_ws, size_t ws_size,
                              hipStream_t stream) {
  const float* x    = (const float*)d_in[0];
  const float* llf  = (const float*)d_in[1];
  const float* W_L  = (const float*)d_in[2];
  const float* b_L  = (const float*)d_in[3];
  const float* W_X  = (const float*)d_in[4];
  const float* g_X  = (const float*)d_in[5];
  const float* be_X = (const float*)d_in[6];
  const float* W_phi = (const float*)d_in[7];
  const float* g_phi = (const float*)d_in[8];
  const float* be_phi = (const float*)d_in[9];
  const float* W_psi = (const float*)d_in[10];
  const float* g_psi = (const float*)d_in[11];
  const float* be_psi = (const float*)d_in[12];
  const float* W_delta = (const float*)d_in[13];
  const float* g_delta = (const float*)d_in[14];
  const float* be_delta = (const float*)d_in[15];
  const float* W_rho = (const float*)d_in[16];
  const float* g_rho = (const float*)d_in[17];
  const float* be_rho = (const float*)d_in[18];
  const float* W_g  = (const float*)d_in[19];
  const float* g_g  = (const float*)d_in[20];
  const float* be_g = (const float*)d_in[21];
  const float* W_out = (const float*)d_in[22];
  const float* b_out = (const float*)d_in[23];

  float* ws = (float*)d_ws;
  float* Xf = ws;                                        // 8388608 fl, persistent (raw conv out)
  float* U  = ws + 8388608;
  // conv-stage aliases (dead after conv):
  unsigned short* xT = (unsigned short*)U;               // 35684352 u16 = 17842176 fl
  unsigned short* WT = (unsigned short*)(U + 17842176);  // 9437184 u16 (ends 22560768 fl)
  // post-conv buffers (overlap xT/WT region):
  unsigned short* concat_h = (unsigned short*)U;         // [b][4096][1024] f16 = 8388608 fl
  float* key  = U + 8388608;                             // 4194304 fl (raw)
  float* Xbar = U + 12582912;                            // 8388608 fl (raw, ends 20971520)
  // small region beyond WT end (never overlaps conv data):
  float* SM   = U + 22560768;
  float* M     = SM;                                     // 311296
  float* attnb = SM + 311296;                            // 311296
  float* fk    = SM + 622592;                            // 38912
  float* qry   = SM + 661504;                            // 19456
  float* dlt   = SM + 680960;                            // 19456
  float* Wd    = SM + 700416;                            // 38912
  float* st    = SM + 739328;                            // 4096
  unsigned short* Wpsi_h = (unsigned short*)(SM + 743424);  // 131072 u16
  unsigned short* Wg_h   = (unsigned short*)(SM + 808960);  // 524288 u16
  float* scX = st,        *shX = st + 512;
  float* scP = st + 1024, *shP = st + 1280;
  float* scR = st + 1536, *shR = st + 2048;
  float* scG = st + 2560, *shG = st + 3072;

  // 0. prep: halo-zero + f16 conversions
  hipMemsetAsync(xT, 0, (size_t)35684352 * sizeof(unsigned short), stream);
  ocr_cvt_x<<<dim3(4, 64, 4), 256, 0, stream>>>(x, xT);
  ocr_cvt_w<<<dim3(4096), 256, 0, stream>>>(W_X, WT);
  ocr_cvt_h<<<dim3(512), 256, 0, stream>>>(W_psi, Wpsi_h, 131072);
  ocr_cvt_h<<<dim3(2048), 256, 0, stream>>>(W_g, Wg_h, 524288);

  // 1. conv (f16 MFMA, tap-split, double-buffered, XCD-swizzled) -> Xf raw
  ocr_conv_mfma<<<dim3(256), 512, 0, stream>>>(xT, WT, Xf);

  // 2. BN(X) stats only; apply is fused into t2h and fk
  ocr_chan_stats<<<dim3(512), 256, 0, stream>>>(Xf, g_X, be_X, scX, shX, 512);
  // 3. Xf -> concat_h cols [0,512) f16 transposed (BN+relu fused)
  ocr_t2h<<<dim3(64, 8, 4), 256, 0, stream>>>(Xf, scX, shX, concat_h, 512, 0);
  // 4. region head: L -> softmax -> f_k (BN fused) -> query/delta + BN76
  ocr_lproj<<<dim3(64, 4), 256, 0, stream>>>(llf, W_L, b_L, M);
  ocr_softmax4096<<<dim3(76), 256, 0, stream>>>(M);
  ocr_fk<<<dim3(512, 4), 256, 0, stream>>>(M, Xf, scX, shX, fk);
  ocr_qd<<<dim3(76), 256, 0, stream>>>(W_phi, fk, qry);
  ocr_qd<<<dim3(76), 256, 0, stream>>>(W_delta, fk, dlt);
  ocr_bn76<<<dim3(256), 128, 0, stream>>>(qry, g_phi, be_phi);
  ocr_bn76<<<dim3(256), 128, 0, stream>>>(dlt, g_delta, be_delta);
  // 5. key_raw = W_psi @ concat (f16 MFMA); BN stats; apply fused into attn
  ocr_gemm_h<512, 64, 128, 2, 2, 1024><<<dim3(32, 4, 4), 256, 0, stream>>>(Wpsi_h, concat_h, key, 256);
  ocr_chan_stats<<<dim3(256), 256, 0, stream>>>(key, g_psi, be_psi, scP, shP, 256);
  // 6. attention softmax over nc (key BN+relu fused)
  ocr_attn<<<dim3(64, 4), 256, 0, stream>>>(qry, key, scP, shP, attnb);
  // 7. X_obj = BN(relu(W_rho @ delta @ attn)) via associativity (K=19)
  ocr_wd<<<dim3(152), 256, 0, stream>>>(W_rho, dlt, Wd);
  ocr_xobj_stats<<<dim3(512), 256, 0, stream>>>(Wd, attnb, g_rho, be_rho, scR, shR);
  ocr_xobj_apply<<<dim3(16, 4), 512, 0, stream>>>(Wd, attnb, scR, shR, concat_h);
  // 8. Xbar_raw = W_g @ concat (f16 MFMA, K=1024); BN stats; apply fused in out
  ocr_gemm_h<1024, 128, 128, 2, 2, 1024><<<dim3(32, 4, 4), 256, 0, stream>>>(Wg_h, concat_h, Xbar, 512);
  ocr_chan_stats<<<dim3(512), 256, 0, stream>>>(Xbar, g_g, be_g, scG, shG, 512);
  // 9. output projection (Xbar BN+relu fused)
  ocr_out<<<dim3(64, 4), 256, 0, stream>>>(W_out, b_out, Xbar, scG, shG, (float*)d_out);
}